// Round 1
// baseline (505.020 us; speedup 1.0000x reference)
//
#include <hip/hip_runtime.h>
#include <cstdint>
#include <cstddef>

// GNN: SAGEConv(mean) + GATConv(1 head, self-loops) + log_softmax
// Strategy: build CSR by dst (hist -> scan -> scatter), then per-node
// atomic-free aggregation kernels. Node GEMMs as one fused LDS-tiled kernel.

#define IN_C 64
#define HID_C 64
#define OUT_C 32

// ---------------- CSR build ----------------

__global__ __launch_bounds__(256) void k_hist(const int* __restrict__ ei, int* __restrict__ deg, int E) {
    int e = blockIdx.x * 256 + threadIdx.x;
    if (e < E) atomicAdd(&deg[ei[E + e]], 1);   // dst row
}

__global__ __launch_bounds__(256) void k_scanA(const int* __restrict__ deg, int* __restrict__ bsum, int N) {
    __shared__ int t[256];
    int tid = threadIdx.x;
    int base = blockIdx.x * 4096 + tid * 16;
    int s = 0;
    #pragma unroll
    for (int u = 0; u < 16; ++u) { int idx = base + u; s += (idx < N) ? deg[idx] : 0; }
    t[tid] = s; __syncthreads();
    for (int off = 128; off; off >>= 1) { if (tid < off) t[tid] += t[tid + off]; __syncthreads(); }
    if (tid == 0) bsum[blockIdx.x] = t[0];
}

__global__ void k_scanB(const int* __restrict__ bsum, int* __restrict__ boff, int* __restrict__ rowptr, int nb, int N) {
    if (threadIdx.x == 0 && blockIdx.x == 0) {
        int run = 0;
        for (int b = 0; b < nb; ++b) { boff[b] = run; run += bsum[b]; }
        rowptr[N] = run;
    }
}

__global__ __launch_bounds__(256) void k_scanC(const int* __restrict__ deg, const int* __restrict__ boff,
                                               int* __restrict__ rowptr, int N) {
    __shared__ int t[256];
    int tid = threadIdx.x;
    int base = blockIdx.x * 4096 + tid * 16;
    int loc[16];
    int s = 0;
    #pragma unroll
    for (int u = 0; u < 16; ++u) {
        int idx = base + u;
        int v = (idx < N) ? deg[idx] : 0;
        loc[u] = s; s += v;
    }
    t[tid] = s; __syncthreads();
    // Hillis-Steele inclusive scan
    for (int off = 1; off < 256; off <<= 1) {
        int v = (tid >= off) ? t[tid - off] : 0;
        __syncthreads();
        t[tid] += v;
        __syncthreads();
    }
    int tpre = (tid > 0) ? t[tid - 1] : 0;
    int off0 = boff[blockIdx.x] + tpre;
    #pragma unroll
    for (int u = 0; u < 16; ++u) {
        int idx = base + u;
        if (idx < N) rowptr[idx] = off0 + loc[u];
    }
}

__global__ __launch_bounds__(256) void k_scatter(const int* __restrict__ ei, const int* __restrict__ rowptr,
                                                 int* __restrict__ cnt, int* __restrict__ csr, int E) {
    int e = blockIdx.x * 256 + threadIdx.x;
    if (e < E) {
        int d = ei[E + e];
        int p = rowptr[d] + atomicAdd(&cnt[d], 1);
        csr[p] = ei[e];   // src
    }
}

// ---------------- SAGE mean aggregation: wave per node, lane = channel ----------------

__global__ __launch_bounds__(256) void k_gather(const float* __restrict__ x, const int* __restrict__ rowptr,
                                                const int* __restrict__ csr, float* __restrict__ agg, int N) {
    int lane = threadIdx.x & 63;
    int i = blockIdx.x * 4 + (threadIdx.x >> 6);
    if (i >= N) return;
    int r0 = rowptr[i], r1 = rowptr[i + 1];
    float acc = 0.f;
    int j = r0;
    for (; j + 3 < r1; j += 4) {
        int s0 = csr[j], s1 = csr[j + 1], s2 = csr[j + 2], s3 = csr[j + 3];
        float v0 = x[s0 * 64 + lane];
        float v1 = x[s1 * 64 + lane];
        float v2 = x[s2 * 64 + lane];
        float v3 = x[s3 * 64 + lane];
        acc += v0 + v1 + v2 + v3;
    }
    for (; j < r1; ++j) acc += x[csr[j] * 64 + lane];
    float dnorm = fmaxf((float)(r1 - r0), 1.0f);
    agg[i * 64 + lane] = acc / dnorm;
}

// ---------------- Fused node GEMMs: h = relu(agg@Wl + x@Wr + b1); z = h@Wg ----------------
// 64-node M-tile per block, 256 threads as 16x16 with 4x4 register tiles.

__global__ __launch_bounds__(256) void k_gemm(const float* __restrict__ agg, const float* __restrict__ x,
                                              const float* __restrict__ Wl, const float* __restrict__ Wr,
                                              const float* __restrict__ b1, const float* __restrict__ Wg,
                                              float* __restrict__ z, int N) {
    __shared__ alignas(16) float Ws[128 * 64];   // [0:64) = Wl rows, [64:128) = Wr rows  (32 KB)
    __shared__ alignas(16) float Wgs[64 * 32];   // 8 KB
    __shared__ alignas(16) float As[64 * 68];    // k-major A tile, padded stride 68 (17.4 KB)
    int tid = threadIdx.x;
    for (int i = tid; i < 64 * 64; i += 256) { Ws[i] = Wl[i]; Ws[64 * 64 + i] = Wr[i]; }
    for (int i = tid; i < 64 * 32; i += 256) Wgs[i] = Wg[i];
    int m0 = blockIdx.x * 64;
    int tx = tid & 15, ty = tid >> 4;

    float acc[4][4] = {};
    const float* srcs[2] = { agg, x };
    for (int p = 0; p < 2; ++p) {
        __syncthreads();   // protect As (weights staging / previous pass reads)
        #pragma unroll
        for (int l = 0; l < 4; ++l) {
            int idx = tid + l * 256;          // 0..1023
            int m = idx >> 4, kq = idx & 15;  // row, float4-col
            float4 v = { 0.f, 0.f, 0.f, 0.f };
            if (m0 + m < N) v = *(const float4*)(srcs[p] + (size_t)(m0 + m) * 64 + kq * 4);
            As[(kq * 4 + 0) * 68 + m] = v.x;
            As[(kq * 4 + 1) * 68 + m] = v.y;
            As[(kq * 4 + 2) * 68 + m] = v.z;
            As[(kq * 4 + 3) * 68 + m] = v.w;
        }
        __syncthreads();
        const float* wbase = Ws + p * 64 * 64;
        #pragma unroll 8
        for (int k = 0; k < 64; ++k) {
            float4 a = *(const float4*)&As[k * 68 + ty * 4];
            float4 b = *(const float4*)&wbase[k * 64 + tx * 4];
            acc[0][0] += a.x * b.x; acc[0][1] += a.x * b.y; acc[0][2] += a.x * b.z; acc[0][3] += a.x * b.w;
            acc[1][0] += a.y * b.x; acc[1][1] += a.y * b.y; acc[1][2] += a.y * b.z; acc[1][3] += a.y * b.w;
            acc[2][0] += a.z * b.x; acc[2][1] += a.z * b.y; acc[2][2] += a.z * b.z; acc[2][3] += a.z * b.w;
            acc[3][0] += a.w * b.x; acc[3][1] += a.w * b.y; acc[3][2] += a.w * b.z; acc[3][3] += a.w * b.w;
        }
    }
    __syncthreads();   // done reading As; reuse it for relu(h) in k-major layout
    #pragma unroll
    for (int r = 0; r < 4; ++r)
        #pragma unroll
        for (int c = 0; c < 4; ++c) {
            float h = acc[r][c] + b1[tx * 4 + c];
            As[(tx * 4 + c) * 68 + ty * 4 + r] = fmaxf(h, 0.f);
        }
    __syncthreads();
    float acc2[4][2] = {};
    #pragma unroll 8
    for (int k = 0; k < 64; ++k) {
        float4 a = *(const float4*)&As[k * 68 + ty * 4];
        float g0 = Wgs[k * 32 + tx * 2], g1 = Wgs[k * 32 + tx * 2 + 1];
        acc2[0][0] += a.x * g0; acc2[0][1] += a.x * g1;
        acc2[1][0] += a.y * g0; acc2[1][1] += a.y * g1;
        acc2[2][0] += a.z * g0; acc2[2][1] += a.z * g1;
        acc2[3][0] += a.w * g0; acc2[3][1] += a.w * g1;
    }
    #pragma unroll
    for (int r = 0; r < 4; ++r) {
        int m = m0 + ty * 4 + r;
        if (m < N) {
            float2 v = { acc2[r][0], acc2[r][1] };
            *(float2*)(z + (size_t)m * 32 + tx * 2) = v;
        }
    }
}

// ---------------- per-node attention scores a_s = z.att_src, a_d = z.att_dst ----------------

__global__ __launch_bounds__(256) void k_az(const float* __restrict__ z, const float* __restrict__ att_src,
                                            const float* __restrict__ att_dst,
                                            float* __restrict__ a_s, float* __restrict__ a_d, int N) {
    int wid = blockIdx.x * 4 + (threadIdx.x >> 6);
    int half = (threadIdx.x >> 5) & 1;
    int c = threadIdx.x & 31;
    int i = wid * 2 + half;
    float zv = (i < N) ? z[(size_t)i * 32 + c] : 0.f;
    float ps = zv * att_src[c];
    float pd = zv * att_dst[c];
    #pragma unroll
    for (int off = 16; off; off >>= 1) {
        ps += __shfl_down(ps, off, 32);
        pd += __shfl_down(pd, off, 32);
    }
    if (c == 0 && i < N) { a_s[i] = ps; a_d[i] = pd; }
}

// ---------------- GAT softmax aggregation + bias + log_softmax ----------------
// wave per node: pass1 lane-parallel max, pass2 serial edges x 32-channel lanes.

__global__ __launch_bounds__(256) void k_gat(const float* __restrict__ z, const float* __restrict__ a_s,
                                             const float* __restrict__ a_d, const int* __restrict__ rowptr,
                                             const int* __restrict__ csr, const float* __restrict__ b2,
                                             float* __restrict__ out, int N) {
    int lane = threadIdx.x & 63;
    int i = blockIdx.x * 4 + (threadIdx.x >> 6);
    if (i >= N) return;
    int r0 = rowptr[i], r1 = rowptr[i + 1];
    float adi = a_d[i], asi = a_s[i];

    float mx = -3.0e38f;
    for (int j = r0 + lane; j < r1; j += 64) {
        float e = a_s[csr[j]] + adi;
        e = (e >= 0.f) ? e : 0.2f * e;
        mx = fmaxf(mx, e);
    }
    #pragma unroll
    for (int off = 32; off; off >>= 1) mx = fmaxf(mx, __shfl_xor(mx, off, 64));
    float es = asi + adi; es = (es >= 0.f) ? es : 0.2f * es;
    mx = fmaxf(mx, es);

    int c = lane & 31;
    float denom = 0.f, acc = 0.f;
    int j = r0;
    for (; j + 1 < r1; j += 2) {
        int s0 = csr[j], s1 = csr[j + 1];
        float e0 = a_s[s0] + adi; e0 = (e0 >= 0.f) ? e0 : 0.2f * e0;
        float e1 = a_s[s1] + adi; e1 = (e1 >= 0.f) ? e1 : 0.2f * e1;
        float w0 = expf(e0 - mx), w1 = expf(e1 - mx);
        float z0 = z[(size_t)s0 * 32 + c], z1 = z[(size_t)s1 * 32 + c];
        denom += w0 + w1;
        acc += w0 * z0 + w1 * z1;
    }
    for (; j < r1; ++j) {
        int s0 = csr[j];
        float e0 = a_s[s0] + adi; e0 = (e0 >= 0.f) ? e0 : 0.2f * e0;
        float w0 = expf(e0 - mx);
        denom += w0;
        acc += w0 * z[(size_t)s0 * 32 + c];
    }
    float wse = expf(es - mx);
    denom += wse;
    acc += wse * z[(size_t)i * 32 + c];

    float o = acc / denom + b2[c];
    float m2 = o;
    #pragma unroll
    for (int off = 16; off; off >>= 1) m2 = fmaxf(m2, __shfl_xor(m2, off, 32));
    float ex = expf(o - m2);
    float ssum = ex;
    #pragma unroll
    for (int off = 16; off; off >>= 1) ssum += __shfl_xor(ssum, off, 32);
    float res = o - m2 - logf(ssum);
    if (lane < 32) out[(size_t)i * 32 + lane] = res;
}

// ---------------- host launch ----------------

extern "C" void kernel_launch(void* const* d_in, const int* in_sizes, int n_in,
                              void* d_out, int out_size, void* d_ws, size_t ws_size,
                              hipStream_t stream) {
    const float* x       = (const float*)d_in[0];
    const int*   ei      = (const int*)d_in[1];
    const float* Wl      = (const float*)d_in[2];
    const float* Wr      = (const float*)d_in[3];
    const float* b1      = (const float*)d_in[4];
    const float* Wg      = (const float*)d_in[5];
    const float* att_src = (const float*)d_in[6];
    const float* att_dst = (const float*)d_in[7];
    const float* b2      = (const float*)d_in[8];
    float* out = (float*)d_out;

    int N = in_sizes[0] / 64;
    int E = in_sizes[1] / 2;

    char* ws = (char*)d_ws;
    size_t off = 0;
    auto alloc = [&](size_t bytes) { size_t r = off; off += (bytes + 255) & ~(size_t)255; return r; };
    int* deg    = (int*)(ws + alloc((size_t)N * 4));
    int* cnt    = (int*)(ws + alloc((size_t)N * 4));
    int* rowptr = (int*)(ws + alloc((size_t)(N + 1) * 4));
    int* bsum   = (int*)(ws + alloc(256 * 4));
    int* boff   = (int*)(ws + alloc(256 * 4));
    int* csr    = (int*)(ws + alloc((size_t)E * 4));
    float* agg  = (float*)(ws + alloc((size_t)N * 64 * 4));
    float* z    = (float*)(ws + alloc((size_t)N * 32 * 4));
    float* a_s  = (float*)(ws + alloc((size_t)N * 4));
    float* a_d  = (float*)(ws + alloc((size_t)N * 4));

    hipMemsetAsync(deg, 0, (size_t)N * 4, stream);
    hipMemsetAsync(cnt, 0, (size_t)N * 4, stream);

    int nb = (N + 4095) / 4096;
    k_hist   <<<(E + 255) / 256, 256, 0, stream>>>(ei, deg, E);
    k_scanA  <<<nb, 256, 0, stream>>>(deg, bsum, N);
    k_scanB  <<<1, 64, 0, stream>>>(bsum, boff, rowptr, nb, N);
    k_scanC  <<<nb, 256, 0, stream>>>(deg, boff, rowptr, N);
    k_scatter<<<(E + 255) / 256, 256, 0, stream>>>(ei, rowptr, cnt, csr, E);
    k_gather <<<(N + 3) / 4, 256, 0, stream>>>(x, rowptr, csr, agg, N);
    k_gemm   <<<(N + 63) / 64, 256, 0, stream>>>(agg, x, Wl, Wr, b1, Wg, z, N);
    k_az     <<<(N + 7) / 8, 256, 0, stream>>>(z, att_src, att_dst, a_s, a_d, N);
    k_gat    <<<(N + 3) / 4, 256, 0, stream>>>(z, a_s, a_d, rowptr, csr, b2, out, N);
}

// Round 2
// 416.756 us; speedup vs baseline: 1.2118x; 1.2118x over previous
//
#include <hip/hip_runtime.h>
#include <cstdint>
#include <cstddef>

// GNN: SAGEConv(mean) + GATConv(1 head, self-loops) + log_softmax
// CSR by dst (hist -> scan -> scatter), then per-node atomic-free aggregation.
// Gathered rows compressed to bf16; quarter-wave (16-lane) edge parallelism.

typedef unsigned short ushort_t;
typedef unsigned int uint_t;

__device__ inline ushort_t f2bf(float f) {
    uint_t u = __float_as_uint(f);
    uint_t r = (u + 0x7fffu + ((u >> 16) & 1u)) >> 16;   // RTNE
    return (ushort_t)r;
}
__device__ inline float bf_lo(uint_t u) { return __uint_as_float(u << 16); }
__device__ inline float bf_hi(uint_t u) { return __uint_as_float(u & 0xffff0000u); }

// ---------------- CSR build ----------------

__global__ __launch_bounds__(256) void k_hist(const int* __restrict__ ei, int* __restrict__ deg, int E) {
    int e = blockIdx.x * 256 + threadIdx.x;
    if (e < E) atomicAdd(&deg[ei[E + e]], 1);   // dst row
}

__global__ __launch_bounds__(256) void k_scanA(const int* __restrict__ deg, int* __restrict__ bsum, int N) {
    __shared__ int t[256];
    int tid = threadIdx.x;
    int base = blockIdx.x * 4096 + tid * 16;
    int s = 0;
    #pragma unroll
    for (int u = 0; u < 16; ++u) { int idx = base + u; s += (idx < N) ? deg[idx] : 0; }
    t[tid] = s; __syncthreads();
    for (int off = 128; off; off >>= 1) { if (tid < off) t[tid] += t[tid + off]; __syncthreads(); }
    if (tid == 0) bsum[blockIdx.x] = t[0];
}

__global__ void k_scanB(const int* __restrict__ bsum, int* __restrict__ boff, int* __restrict__ rowptr, int nb, int N) {
    if (threadIdx.x == 0 && blockIdx.x == 0) {
        int run = 0;
        for (int b = 0; b < nb; ++b) { boff[b] = run; run += bsum[b]; }
        rowptr[N] = run;
    }
}

__global__ __launch_bounds__(256) void k_scanC(const int* __restrict__ deg, const int* __restrict__ boff,
                                               int* __restrict__ rowptr, int N) {
    __shared__ int t[256];
    int tid = threadIdx.x;
    int base = blockIdx.x * 4096 + tid * 16;
    int loc[16];
    int s = 0;
    #pragma unroll
    for (int u = 0; u < 16; ++u) {
        int idx = base + u;
        int v = (idx < N) ? deg[idx] : 0;
        loc[u] = s; s += v;
    }
    t[tid] = s; __syncthreads();
    for (int off = 1; off < 256; off <<= 1) {
        int v = (tid >= off) ? t[tid - off] : 0;
        __syncthreads();
        t[tid] += v;
        __syncthreads();
    }
    int tpre = (tid > 0) ? t[tid - 1] : 0;
    int off0 = boff[blockIdx.x] + tpre;
    #pragma unroll
    for (int u = 0; u < 16; ++u) {
        int idx = base + u;
        if (idx < N) rowptr[idx] = off0 + loc[u];
    }
}

__global__ __launch_bounds__(256) void k_scatter(const int* __restrict__ ei, const int* __restrict__ rowptr,
                                                 int* __restrict__ cnt, int* __restrict__ csr, int E) {
    int e = blockIdx.x * 256 + threadIdx.x;
    if (e < E) {
        int d = ei[E + e];
        int p = rowptr[d] + atomicAdd(&cnt[d], 1);
        csr[p] = ei[e];   // src
    }
}

// ---------------- x -> bf16 copy ----------------

__global__ __launch_bounds__(256) void k_cvt(const float* __restrict__ x, ushort_t* __restrict__ xh, int n4) {
    int idx = blockIdx.x * 256 + threadIdx.x;
    if (idx < n4) {
        float4 v = ((const float4*)x)[idx];
        ushort4 o = { f2bf(v.x), f2bf(v.y), f2bf(v.z), f2bf(v.w) };
        ((ushort4*)xh)[idx] = o;
    }
}

// ---------------- SAGE mean aggregation ----------------
// wave per node; 4 groups of 16 lanes; each group handles one edge per iter,
// lane cc covers channels 4cc..4cc+3 via a bf16x4 (8 B) load.

__global__ __launch_bounds__(256) void k_gather(const ushort_t* __restrict__ xh, const int* __restrict__ rowptr,
                                                const int* __restrict__ csr, float* __restrict__ agg, int N) {
    int lane = threadIdx.x & 63;
    int i = blockIdx.x * 4 + (threadIdx.x >> 6);
    if (i >= N) return;
    int r0 = rowptr[i], r1 = rowptr[i + 1];
    int g = lane >> 4, cc = lane & 15;
    float a0 = 0.f, a1 = 0.f, a2 = 0.f, a3 = 0.f;
    for (int base = r0; base < r1; base += 64) {
        int cnt = min(64, r1 - base);
        int src_l = (lane < cnt) ? csr[base + lane] : 0;
        int iters = (cnt + 3) >> 2;
        for (int t = 0; t < iters; ++t) {
            int eidx = 4 * t + g;
            bool act = eidx < cnt;
            int s = __shfl(src_l, act ? eidx : 0, 64);
            if (act) {
                uint2 u = *(const uint2*)(xh + (size_t)s * 64 + cc * 4);
                a0 += bf_lo(u.x); a1 += bf_hi(u.x);
                a2 += bf_lo(u.y); a3 += bf_hi(u.y);
            }
        }
    }
    a0 += __shfl_xor(a0, 16, 64); a0 += __shfl_xor(a0, 32, 64);
    a1 += __shfl_xor(a1, 16, 64); a1 += __shfl_xor(a1, 32, 64);
    a2 += __shfl_xor(a2, 16, 64); a2 += __shfl_xor(a2, 32, 64);
    a3 += __shfl_xor(a3, 16, 64); a3 += __shfl_xor(a3, 32, 64);
    float dn = 1.0f / fmaxf((float)(r1 - r0), 1.0f);
    if (lane < 16) {
        float4 v = { a0 * dn, a1 * dn, a2 * dn, a3 * dn };
        *(float4*)(agg + (size_t)i * 64 + cc * 4) = v;
    }
}

// ---------------- Fused node GEMMs + attention scores ----------------
// h = relu(agg@Wl + x@Wr + b1); z = h@Wg (stored bf16); a_s = z.att_src; a_d = z.att_dst

__global__ __launch_bounds__(256) void k_gemm(const float* __restrict__ agg, const float* __restrict__ x,
                                              const float* __restrict__ Wl, const float* __restrict__ Wr,
                                              const float* __restrict__ b1, const float* __restrict__ Wg,
                                              const float* __restrict__ att_src, const float* __restrict__ att_dst,
                                              ushort_t* __restrict__ zh, float* __restrict__ a_s,
                                              float* __restrict__ a_d, int N) {
    __shared__ alignas(16) float Ws[128 * 64];   // Wl rows then Wr rows (32 KB)
    __shared__ alignas(16) float Wgs[64 * 32];   // 8 KB
    __shared__ alignas(16) float As[64 * 68];    // k-major A tile, padded stride 68
    int tid = threadIdx.x;
    for (int i = tid; i < 64 * 64; i += 256) { Ws[i] = Wl[i]; Ws[64 * 64 + i] = Wr[i]; }
    for (int i = tid; i < 64 * 32; i += 256) Wgs[i] = Wg[i];
    int m0 = blockIdx.x * 64;
    int tx = tid & 15, ty = tid >> 4;

    float acc[4][4] = {};
    const float* srcs[2] = { agg, x };
    for (int p = 0; p < 2; ++p) {
        __syncthreads();
        #pragma unroll
        for (int l = 0; l < 4; ++l) {
            int idx = tid + l * 256;
            int m = idx >> 4, kq = idx & 15;
            float4 v = { 0.f, 0.f, 0.f, 0.f };
            if (m0 + m < N) v = *(const float4*)(srcs[p] + (size_t)(m0 + m) * 64 + kq * 4);
            As[(kq * 4 + 0) * 68 + m] = v.x;
            As[(kq * 4 + 1) * 68 + m] = v.y;
            As[(kq * 4 + 2) * 68 + m] = v.z;
            As[(kq * 4 + 3) * 68 + m] = v.w;
        }
        __syncthreads();
        const float* wbase = Ws + p * 64 * 64;
        #pragma unroll 8
        for (int k = 0; k < 64; ++k) {
            float4 a = *(const float4*)&As[k * 68 + ty * 4];
            float4 b = *(const float4*)&wbase[k * 64 + tx * 4];
            acc[0][0] += a.x * b.x; acc[0][1] += a.x * b.y; acc[0][2] += a.x * b.z; acc[0][3] += a.x * b.w;
            acc[1][0] += a.y * b.x; acc[1][1] += a.y * b.y; acc[1][2] += a.y * b.z; acc[1][3] += a.y * b.w;
            acc[2][0] += a.z * b.x; acc[2][1] += a.z * b.y; acc[2][2] += a.z * b.z; acc[2][3] += a.z * b.w;
            acc[3][0] += a.w * b.x; acc[3][1] += a.w * b.y; acc[3][2] += a.w * b.z; acc[3][3] += a.w * b.w;
        }
    }
    __syncthreads();   // reuse As for relu(h), k-major
    #pragma unroll
    for (int r = 0; r < 4; ++r)
        #pragma unroll
        for (int c = 0; c < 4; ++c) {
            float h = acc[r][c] + b1[tx * 4 + c];
            As[(tx * 4 + c) * 68 + ty * 4 + r] = fmaxf(h, 0.f);
        }
    __syncthreads();
    float acc2[4][2] = {};
    #pragma unroll 8
    for (int k = 0; k < 64; ++k) {
        float4 a = *(const float4*)&As[k * 68 + ty * 4];
        float g0 = Wgs[k * 32 + tx * 2], g1 = Wgs[k * 32 + tx * 2 + 1];
        acc2[0][0] += a.x * g0; acc2[0][1] += a.x * g1;
        acc2[1][0] += a.y * g0; acc2[1][1] += a.y * g1;
        acc2[2][0] += a.z * g0; acc2[2][1] += a.z * g1;
        acc2[3][0] += a.w * g0; acc2[3][1] += a.w * g1;
    }
    // epilogue: write zh (bf16) + reduce a_s/a_d across the 16 tx lanes of each ty group
    float as0 = att_src[tx * 2], as1 = att_src[tx * 2 + 1];
    float ad0 = att_dst[tx * 2], ad1 = att_dst[tx * 2 + 1];
    #pragma unroll
    for (int r = 0; r < 4; ++r) {
        int m = m0 + ty * 4 + r;
        float z0 = acc2[r][0], z1 = acc2[r][1];
        float ps = z0 * as0 + z1 * as1;
        float pd = z0 * ad0 + z1 * ad1;
        #pragma unroll
        for (int off = 8; off; off >>= 1) {
            ps += __shfl_xor(ps, off, 64);
            pd += __shfl_xor(pd, off, 64);
        }
        if (m < N) {
            ushort2 zz = { f2bf(z0), f2bf(z1) };
            *(ushort2*)(zh + (size_t)m * 32 + tx * 2) = zz;
            if (tx == 0) { a_s[m] = ps; a_d[m] = pd; }
        }
    }
}

// ---------------- GAT softmax aggregation + bias + log_softmax ----------------
// wave per node. No max subtraction (scores bounded; softmax shift-invariant).
// Phase 1: lane-parallel exp weights (64 edges/instr). Phase 2: quarter-wave
// accumulation (4 edges/iter, lane cc covers channels 2cc,2cc+1 via bf16x2).

__global__ __launch_bounds__(256) void k_gat(const ushort_t* __restrict__ zh, const float* __restrict__ a_s,
                                             const float* __restrict__ a_d, const int* __restrict__ rowptr,
                                             const int* __restrict__ csr, const float* __restrict__ b2,
                                             float* __restrict__ out, int N) {
    int lane = threadIdx.x & 63;
    int i = blockIdx.x * 4 + (threadIdx.x >> 6);
    if (i >= N) return;
    int r0 = rowptr[i], r1 = rowptr[i + 1];
    float adi = a_d[i], asi = a_s[i];
    int g = lane >> 4, cc = lane & 15;

    float accx = 0.f, accy = 0.f, dsum = 0.f;
    for (int base = r0; base < r1; base += 64) {
        int cnt = min(64, r1 - base);
        int src_l = 0; float w_l = 0.f;
        if (lane < cnt) {
            src_l = csr[base + lane];
            float e = a_s[src_l] + adi;
            e = (e >= 0.f) ? e : 0.2f * e;
            w_l = expf(e);
            dsum += w_l;
        }
        int iters = (cnt + 3) >> 2;
        for (int t = 0; t < iters; ++t) {
            int eidx = 4 * t + g;
            bool act = eidx < cnt;
            int sel = act ? eidx : 0;
            int s = __shfl(src_l, sel, 64);
            float w = __shfl(w_l, sel, 64);
            if (act) {
                uint_t u = *(const uint_t*)(zh + (size_t)s * 32 + cc * 2);
                accx += w * bf_lo(u);
                accy += w * bf_hi(u);
            }
        }
    }
    #pragma unroll
    for (int off = 32; off; off >>= 1) dsum += __shfl_xor(dsum, off, 64);
    accx += __shfl_xor(accx, 16, 64); accx += __shfl_xor(accx, 32, 64);
    accy += __shfl_xor(accy, 16, 64); accy += __shfl_xor(accy, 32, 64);

    // self loop
    float es = asi + adi; es = (es >= 0.f) ? es : 0.2f * es;
    float wse = expf(es);
    float denom = dsum + wse;
    uint_t us = *(const uint_t*)(zh + (size_t)i * 32 + cc * 2);
    accx += wse * bf_lo(us);
    accy += wse * bf_hi(us);

    float rden = 1.0f / denom;
    float o0 = accx * rden + b2[cc * 2];
    float o1 = accy * rden + b2[cc * 2 + 1];
    // log_softmax over 32 channels (replicated across the 4 groups)
    float m2 = fmaxf(o0, o1);
    #pragma unroll
    for (int off = 8; off; off >>= 1) m2 = fmaxf(m2, __shfl_xor(m2, off, 64));
    float ssum = expf(o0 - m2) + expf(o1 - m2);
    #pragma unroll
    for (int off = 8; off; off >>= 1) ssum += __shfl_xor(ssum, off, 64);
    float lg = m2 + logf(ssum);
    if (lane < 16) {
        float2 r = { o0 - lg, o1 - lg };
        *(float2*)(out + (size_t)i * 32 + cc * 2) = r;
    }
}

// ---------------- host launch ----------------

extern "C" void kernel_launch(void* const* d_in, const int* in_sizes, int n_in,
                              void* d_out, int out_size, void* d_ws, size_t ws_size,
                              hipStream_t stream) {
    const float* x       = (const float*)d_in[0];
    const int*   ei      = (const int*)d_in[1];
    const float* Wl      = (const float*)d_in[2];
    const float* Wr      = (const float*)d_in[3];
    const float* b1      = (const float*)d_in[4];
    const float* Wg      = (const float*)d_in[5];
    const float* att_src = (const float*)d_in[6];
    const float* att_dst = (const float*)d_in[7];
    const float* b2      = (const float*)d_in[8];
    float* out = (float*)d_out;

    int N = in_sizes[0] / 64;
    int E = in_sizes[1] / 2;

    char* ws = (char*)d_ws;
    size_t off = 0;
    auto alloc = [&](size_t bytes) { size_t r = off; off += (bytes + 255) & ~(size_t)255; return r; };
    int* deg       = (int*)(ws + alloc((size_t)N * 4));
    int* cnt       = (int*)(ws + alloc((size_t)N * 4));
    int* rowptr    = (int*)(ws + alloc((size_t)(N + 1) * 4));
    int* bsum      = (int*)(ws + alloc(256 * 4));
    int* boff      = (int*)(ws + alloc(256 * 4));
    int* csr       = (int*)(ws + alloc((size_t)E * 4));
    ushort_t* xh   = (ushort_t*)(ws + alloc((size_t)N * 64 * 2));
    float* agg     = (float*)(ws + alloc((size_t)N * 64 * 4));
    ushort_t* zh   = (ushort_t*)(ws + alloc((size_t)N * 32 * 2));
    float* a_s     = (float*)(ws + alloc((size_t)N * 4));
    float* a_d     = (float*)(ws + alloc((size_t)N * 4));

    hipMemsetAsync(deg, 0, (size_t)N * 4, stream);
    hipMemsetAsync(cnt, 0, (size_t)N * 4, stream);

    int nb = (N + 4095) / 4096;
    int n4 = N * 64 / 4;
    k_hist   <<<(E + 255) / 256, 256, 0, stream>>>(ei, deg, E);
    k_cvt    <<<(n4 + 255) / 256, 256, 0, stream>>>(x, xh, n4);
    k_scanA  <<<nb, 256, 0, stream>>>(deg, bsum, N);
    k_scanB  <<<1, 64, 0, stream>>>(bsum, boff, rowptr, nb, N);
    k_scanC  <<<nb, 256, 0, stream>>>(deg, boff, rowptr, N);
    k_scatter<<<(E + 255) / 256, 256, 0, stream>>>(ei, rowptr, cnt, csr, E);
    k_gather <<<(N + 3) / 4, 256, 0, stream>>>(xh, rowptr, csr, agg, N);
    k_gemm   <<<(N + 63) / 64, 256, 0, stream>>>(agg, x, Wl, Wr, b1, Wg, att_src, att_dst, zh, a_s, a_d, N);
    k_gat    <<<(N + 3) / 4, 256, 0, stream>>>(zh, a_s, a_d, rowptr, csr, b2, out, N);
}

// Round 3
// 303.272 us; speedup vs baseline: 1.6652x; 1.3742x over previous
//
#include <hip/hip_runtime.h>
#include <cstdint>
#include <cstddef>

// GNN: SAGEConv(mean) + GATConv(1 head, self-loops) + log_softmax
// CSR built via two-level counting sort (bucket = dst>>8) with LDS-aggregated
// atomics; per-node atomic-free aggregation; gathered rows in bf16.

typedef unsigned short ushort_t;
typedef unsigned int uint_t;

__device__ inline ushort_t f2bf(float f) {
    uint_t u = __float_as_uint(f);
    uint_t r = (u + 0x7fffu + ((u >> 16) & 1u)) >> 16;   // RTNE
    return (ushort_t)r;
}
__device__ inline float bf_lo(uint_t u) { return __uint_as_float(u << 16); }
__device__ inline float bf_hi(uint_t u) { return __uint_as_float(u & 0xffff0000u); }

#define PART_CHUNK 8192   // edges per block in k_cnt / k_part

// ---------------- CSR build: counting sort ----------------

// P1: per-bucket edge counts (LDS histogram, one global atomic per block-bucket)
__global__ __launch_bounds__(256) void k_cnt(const int* __restrict__ ei, int* __restrict__ tot, int E, int NB) {
    __shared__ int h[512];
    int tid = threadIdx.x;
    for (int b = tid; b < NB; b += 256) h[b] = 0;
    __syncthreads();
    int b0 = blockIdx.x * PART_CHUNK;
    int b1 = min(b0 + PART_CHUNK, E);
    for (int j = b0 + tid; j < b1; j += 256) atomicAdd(&h[ei[E + j] >> 8], 1);
    __syncthreads();
    for (int b = tid; b < NB; b += 256) if (h[b]) atomicAdd(&tot[b], h[b]);
}

// P2: exclusive scan of bucket totals -> base[], gofs[] (running cursors)
__global__ __launch_bounds__(256) void k_scan(const int* __restrict__ tot, int* __restrict__ base,
                                              int* __restrict__ gofs, int* __restrict__ rowptr,
                                              int NB, int E, int N) {
    __shared__ int t[256];
    int tid = threadIdx.x;
    int v0 = (2 * tid < NB) ? tot[2 * tid] : 0;
    int v1 = (2 * tid + 1 < NB) ? tot[2 * tid + 1] : 0;
    t[tid] = v0 + v1;
    __syncthreads();
    for (int off = 1; off < 256; off <<= 1) {
        int u = (tid >= off) ? t[tid - off] : 0;
        __syncthreads();
        t[tid] += u;
        __syncthreads();
    }
    int pairExcl = (tid > 0) ? t[tid - 1] : 0;
    if (2 * tid < NB)     { base[2 * tid] = pairExcl;      gofs[2 * tid] = pairExcl; }
    if (2 * tid + 1 < NB) { base[2 * tid + 1] = pairExcl + v0; gofs[2 * tid + 1] = pairExcl + v0; }
    if (tid == 0) { rowptr[N] = E; base[NB] = E; }
}

// P3: partition (src,dst) pairs into bucket-contiguous order
__global__ __launch_bounds__(256) void k_part(const int* __restrict__ ei, int* __restrict__ gofs,
                                              int2* __restrict__ pairs, int E, int NB) {
    __shared__ int h[512];
    __shared__ int ofs[512];
    int tid = threadIdx.x;
    for (int b = tid; b < NB; b += 256) h[b] = 0;
    __syncthreads();
    int b0 = blockIdx.x * PART_CHUNK;
    int b1 = min(b0 + PART_CHUNK, E);
    for (int j = b0 + tid; j < b1; j += 256) atomicAdd(&h[ei[E + j] >> 8], 1);
    __syncthreads();
    for (int b = tid; b < NB; b += 256) ofs[b] = h[b] ? atomicAdd(&gofs[b], h[b]) : 0;
    __syncthreads();
    for (int j = b0 + tid; j < b1; j += 256) {
        int d = ei[E + j], s = ei[j];
        int p = atomicAdd(&ofs[d >> 8], 1);
        pairs[p] = make_int2(s, d);
    }
}

// P4: per-bucket CSR: in-LDS degree count + scan -> rowptr, then windowed scatter
__global__ __launch_bounds__(256) void k_csr(const int2* __restrict__ pairs, const int* __restrict__ base,
                                             int* __restrict__ rowptr, int* __restrict__ csr, int N) {
    __shared__ int h[256];
    __shared__ int s[256];
    int b = blockIdx.x;
    int d0 = b << 8;
    int e0 = base[b], e1 = base[b + 1];
    int tid = threadIdx.x;
    h[tid] = 0;
    __syncthreads();
    for (int j = e0 + tid; j < e1; j += 256) atomicAdd(&h[pairs[j].y & 255], 1);
    __syncthreads();
    int v = h[tid];
    s[tid] = v;
    __syncthreads();
    for (int off = 1; off < 256; off <<= 1) {
        int u = (tid >= off) ? s[tid - off] : 0;
        __syncthreads();
        s[tid] += u;
        __syncthreads();
    }
    int excl = s[tid] - v;
    int d = d0 + tid;
    if (d < N) rowptr[d] = e0 + excl;
    __syncthreads();
    h[tid] = e0 + excl;   // running write cursor per node
    __syncthreads();
    for (int j = e0 + tid; j < e1; j += 256) {
        int2 p = pairs[j];
        int pos = atomicAdd(&h[p.y & 255], 1);
        csr[pos] = p.x;
    }
}

// ---------------- x -> bf16 copy ----------------

__global__ __launch_bounds__(256) void k_cvt(const float* __restrict__ x, ushort_t* __restrict__ xh, int n4) {
    int idx = blockIdx.x * 256 + threadIdx.x;
    if (idx < n4) {
        float4 v = ((const float4*)x)[idx];
        ushort4 o = { f2bf(v.x), f2bf(v.y), f2bf(v.z), f2bf(v.w) };
        ((ushort4*)xh)[idx] = o;
    }
}

// ---------------- SAGE mean aggregation ----------------
// wave per node; 4 groups of 16 lanes; each group handles one edge per iter,
// lane cc covers channels 4cc..4cc+3 via a bf16x4 (8 B) load.

__global__ __launch_bounds__(256) void k_gather(const ushort_t* __restrict__ xh, const int* __restrict__ rowptr,
                                                const int* __restrict__ csr, float* __restrict__ agg, int N) {
    int lane = threadIdx.x & 63;
    int i = blockIdx.x * 4 + (threadIdx.x >> 6);
    if (i >= N) return;
    int r0 = rowptr[i], r1 = rowptr[i + 1];
    int g = lane >> 4, cc = lane & 15;
    float a0 = 0.f, a1 = 0.f, a2 = 0.f, a3 = 0.f;
    for (int base = r0; base < r1; base += 64) {
        int cnt = min(64, r1 - base);
        int src_l = (lane < cnt) ? csr[base + lane] : 0;
        int iters = (cnt + 3) >> 2;
        for (int t = 0; t < iters; ++t) {
            int eidx = 4 * t + g;
            bool act = eidx < cnt;
            int s = __shfl(src_l, act ? eidx : 0, 64);
            if (act) {
                uint2 u = *(const uint2*)(xh + (size_t)s * 64 + cc * 4);
                a0 += bf_lo(u.x); a1 += bf_hi(u.x);
                a2 += bf_lo(u.y); a3 += bf_hi(u.y);
            }
        }
    }
    a0 += __shfl_xor(a0, 16, 64); a0 += __shfl_xor(a0, 32, 64);
    a1 += __shfl_xor(a1, 16, 64); a1 += __shfl_xor(a1, 32, 64);
    a2 += __shfl_xor(a2, 16, 64); a2 += __shfl_xor(a2, 32, 64);
    a3 += __shfl_xor(a3, 16, 64); a3 += __shfl_xor(a3, 32, 64);
    float dn = 1.0f / fmaxf((float)(r1 - r0), 1.0f);
    if (lane < 16) {
        float4 v = { a0 * dn, a1 * dn, a2 * dn, a3 * dn };
        *(float4*)(agg + (size_t)i * 64 + cc * 4) = v;
    }
}

// ---------------- Fused node GEMMs + attention scores ----------------
// h = relu(agg@Wl + x@Wr + b1); z = h@Wg (stored bf16); a_s = z.att_src; a_d = z.att_dst

__global__ __launch_bounds__(256) void k_gemm(const float* __restrict__ agg, const float* __restrict__ x,
                                              const float* __restrict__ Wl, const float* __restrict__ Wr,
                                              const float* __restrict__ b1, const float* __restrict__ Wg,
                                              const float* __restrict__ att_src, const float* __restrict__ att_dst,
                                              ushort_t* __restrict__ zh, float* __restrict__ a_s,
                                              float* __restrict__ a_d, int N) {
    __shared__ alignas(16) float Ws[128 * 64];   // Wl rows then Wr rows (32 KB)
    __shared__ alignas(16) float Wgs[64 * 32];   // 8 KB
    __shared__ alignas(16) float As[64 * 68];    // k-major A tile, padded stride 68
    int tid = threadIdx.x;
    for (int i = tid; i < 64 * 64; i += 256) { Ws[i] = Wl[i]; Ws[64 * 64 + i] = Wr[i]; }
    for (int i = tid; i < 64 * 32; i += 256) Wgs[i] = Wg[i];
    int m0 = blockIdx.x * 64;
    int tx = tid & 15, ty = tid >> 4;

    float acc[4][4] = {};
    const float* srcs[2] = { agg, x };
    for (int p = 0; p < 2; ++p) {
        __syncthreads();
        #pragma unroll
        for (int l = 0; l < 4; ++l) {
            int idx = tid + l * 256;
            int m = idx >> 4, kq = idx & 15;
            float4 v = { 0.f, 0.f, 0.f, 0.f };
            if (m0 + m < N) v = *(const float4*)(srcs[p] + (size_t)(m0 + m) * 64 + kq * 4);
            As[(kq * 4 + 0) * 68 + m] = v.x;
            As[(kq * 4 + 1) * 68 + m] = v.y;
            As[(kq * 4 + 2) * 68 + m] = v.z;
            As[(kq * 4 + 3) * 68 + m] = v.w;
        }
        __syncthreads();
        const float* wbase = Ws + p * 64 * 64;
        #pragma unroll 8
        for (int k = 0; k < 64; ++k) {
            float4 a = *(const float4*)&As[k * 68 + ty * 4];
            float4 b = *(const float4*)&wbase[k * 64 + tx * 4];
            acc[0][0] += a.x * b.x; acc[0][1] += a.x * b.y; acc[0][2] += a.x * b.z; acc[0][3] += a.x * b.w;
            acc[1][0] += a.y * b.x; acc[1][1] += a.y * b.y; acc[1][2] += a.y * b.z; acc[1][3] += a.y * b.w;
            acc[2][0] += a.z * b.x; acc[2][1] += a.z * b.y; acc[2][2] += a.z * b.z; acc[2][3] += a.z * b.w;
            acc[3][0] += a.w * b.x; acc[3][1] += a.w * b.y; acc[3][2] += a.w * b.z; acc[3][3] += a.w * b.w;
        }
    }
    __syncthreads();   // reuse As for relu(h), k-major
    #pragma unroll
    for (int r = 0; r < 4; ++r)
        #pragma unroll
        for (int c = 0; c < 4; ++c) {
            float h = acc[r][c] + b1[tx * 4 + c];
            As[(tx * 4 + c) * 68 + ty * 4 + r] = fmaxf(h, 0.f);
        }
    __syncthreads();
    float acc2[4][2] = {};
    #pragma unroll 8
    for (int k = 0; k < 64; ++k) {
        float4 a = *(const float4*)&As[k * 68 + ty * 4];
        float g0 = Wgs[k * 32 + tx * 2], g1 = Wgs[k * 32 + tx * 2 + 1];
        acc2[0][0] += a.x * g0; acc2[0][1] += a.x * g1;
        acc2[1][0] += a.y * g0; acc2[1][1] += a.y * g1;
        acc2[2][0] += a.z * g0; acc2[2][1] += a.z * g1;
        acc2[3][0] += a.w * g0; acc2[3][1] += a.w * g1;
    }
    float as0 = att_src[tx * 2], as1 = att_src[tx * 2 + 1];
    float ad0 = att_dst[tx * 2], ad1 = att_dst[tx * 2 + 1];
    #pragma unroll
    for (int r = 0; r < 4; ++r) {
        int m = m0 + ty * 4 + r;
        float z0 = acc2[r][0], z1 = acc2[r][1];
        float ps = z0 * as0 + z1 * as1;
        float pd = z0 * ad0 + z1 * ad1;
        #pragma unroll
        for (int off = 8; off; off >>= 1) {
            ps += __shfl_xor(ps, off, 64);
            pd += __shfl_xor(pd, off, 64);
        }
        if (m < N) {
            ushort2 zz = { f2bf(z0), f2bf(z1) };
            *(ushort2*)(zh + (size_t)m * 32 + tx * 2) = zz;
            if (tx == 0) { a_s[m] = ps; a_d[m] = pd; }
        }
    }
}

// ---------------- GAT softmax aggregation + bias + log_softmax ----------------
// wave per node. No max subtraction (scores bounded; softmax shift-invariant).

__global__ __launch_bounds__(256) void k_gat(const ushort_t* __restrict__ zh, const float* __restrict__ a_s,
                                             const float* __restrict__ a_d, const int* __restrict__ rowptr,
                                             const int* __restrict__ csr, const float* __restrict__ b2,
                                             float* __restrict__ out, int N) {
    int lane = threadIdx.x & 63;
    int i = blockIdx.x * 4 + (threadIdx.x >> 6);
    if (i >= N) return;
    int r0 = rowptr[i], r1 = rowptr[i + 1];
    float adi = a_d[i], asi = a_s[i];
    int g = lane >> 4, cc = lane & 15;

    float accx = 0.f, accy = 0.f, dsum = 0.f;
    for (int base = r0; base < r1; base += 64) {
        int cnt = min(64, r1 - base);
        int src_l = 0; float w_l = 0.f;
        if (lane < cnt) {
            src_l = csr[base + lane];
            float e = a_s[src_l] + adi;
            e = (e >= 0.f) ? e : 0.2f * e;
            w_l = expf(e);
            dsum += w_l;
        }
        int iters = (cnt + 3) >> 2;
        for (int t = 0; t < iters; ++t) {
            int eidx = 4 * t + g;
            bool act = eidx < cnt;
            int sel = act ? eidx : 0;
            int s = __shfl(src_l, sel, 64);
            float w = __shfl(w_l, sel, 64);
            if (act) {
                uint_t u = *(const uint_t*)(zh + (size_t)s * 32 + cc * 2);
                accx += w * bf_lo(u);
                accy += w * bf_hi(u);
            }
        }
    }
    #pragma unroll
    for (int off = 32; off; off >>= 1) dsum += __shfl_xor(dsum, off, 64);
    accx += __shfl_xor(accx, 16, 64); accx += __shfl_xor(accx, 32, 64);
    accy += __shfl_xor(accy, 16, 64); accy += __shfl_xor(accy, 32, 64);

    float es = asi + adi; es = (es >= 0.f) ? es : 0.2f * es;
    float wse = expf(es);
    float denom = dsum + wse;
    uint_t us = *(const uint_t*)(zh + (size_t)i * 32 + cc * 2);
    accx += wse * bf_lo(us);
    accy += wse * bf_hi(us);

    float rden = 1.0f / denom;
    float o0 = accx * rden + b2[cc * 2];
    float o1 = accy * rden + b2[cc * 2 + 1];
    float m2 = fmaxf(o0, o1);
    #pragma unroll
    for (int off = 8; off; off >>= 1) m2 = fmaxf(m2, __shfl_xor(m2, off, 64));
    float ssum = expf(o0 - m2) + expf(o1 - m2);
    #pragma unroll
    for (int off = 8; off; off >>= 1) ssum += __shfl_xor(ssum, off, 64);
    float lg = m2 + logf(ssum);
    if (lane < 16) {
        float2 r = { o0 - lg, o1 - lg };
        *(float2*)(out + (size_t)i * 32 + cc * 2) = r;
    }
}

// ---------------- host launch ----------------

extern "C" void kernel_launch(void* const* d_in, const int* in_sizes, int n_in,
                              void* d_out, int out_size, void* d_ws, size_t ws_size,
                              hipStream_t stream) {
    const float* x       = (const float*)d_in[0];
    const int*   ei      = (const int*)d_in[1];
    const float* Wl      = (const float*)d_in[2];
    const float* Wr      = (const float*)d_in[3];
    const float* b1      = (const float*)d_in[4];
    const float* Wg      = (const float*)d_in[5];
    const float* att_src = (const float*)d_in[6];
    const float* att_dst = (const float*)d_in[7];
    const float* b2      = (const float*)d_in[8];
    float* out = (float*)d_out;

    int N = in_sizes[0] / 64;
    int E = in_sizes[1] / 2;
    int NB = (N + 255) >> 8;           // buckets of 256 dst nodes (<= 512)

    char* ws = (char*)d_ws;
    size_t off = 0;
    auto alloc = [&](size_t bytes) { size_t r = off; off += (bytes + 255) & ~(size_t)255; return r; };
    int* tot       = (int*)(ws + alloc((size_t)(NB + 1) * 4));
    int* base      = (int*)(ws + alloc((size_t)(NB + 1) * 4));
    int* gofs      = (int*)(ws + alloc((size_t)(NB + 1) * 4));
    int* rowptr    = (int*)(ws + alloc((size_t)(N + 1) * 4));
    int2* pairs    = (int2*)(ws + alloc((size_t)E * 8));
    int* csr       = (int*)(ws + alloc((size_t)E * 4));
    ushort_t* xh   = (ushort_t*)(ws + alloc((size_t)N * 64 * 2));
    float* agg     = (float*)(ws + alloc((size_t)N * 64 * 4));
    ushort_t* zh   = (ushort_t*)(ws + alloc((size_t)N * 32 * 2));
    float* a_s     = (float*)(ws + alloc((size_t)N * 4));
    float* a_d     = (float*)(ws + alloc((size_t)N * 4));

    hipMemsetAsync(tot, 0, (size_t)NB * 4, stream);

    int nchunk = (E + PART_CHUNK - 1) / PART_CHUNK;
    int n4 = N * 64 / 4;
    k_cnt    <<<nchunk, 256, 0, stream>>>(ei, tot, E, NB);
    k_cvt    <<<(n4 + 255) / 256, 256, 0, stream>>>(x, xh, n4);
    k_scan   <<<1, 256, 0, stream>>>(tot, base, gofs, rowptr, NB, E, N);
    k_part   <<<nchunk, 256, 0, stream>>>(ei, gofs, pairs, E, NB);
    k_csr    <<<NB, 256, 0, stream>>>(pairs, base, rowptr, csr, N);
    k_gather <<<(N + 3) / 4, 256, 0, stream>>>(xh, rowptr, csr, agg, N);
    k_gemm   <<<(N + 63) / 64, 256, 0, stream>>>(agg, x, Wl, Wr, b1, Wg, att_src, att_dst, zh, a_s, a_d, N);
    k_gat    <<<(N + 3) / 4, 256, 0, stream>>>(zh, a_s, a_d, rowptr, csr, b2, out, N);
}

// Round 5
// 285.328 us; speedup vs baseline: 1.7700x; 1.0629x over previous
//
#include <hip/hip_runtime.h>
#include <cstdint>
#include <cstddef>

// GNN: SAGEConv(mean) + GATConv(1 head, self-loops) + log_softmax
// CSR via two-level counting sort (bucket = dst>>8). Aggregation kernels use
// 16-lane-group-per-node with macro-unrolled ds_swizzle-broadcast inner loops.

typedef unsigned short ushort_t;
typedef unsigned int uint_t;

__device__ inline ushort_t f2bf(float f) {
    uint_t u = __float_as_uint(f);
    uint_t r = (u + 0x7fffu + ((u >> 16) & 1u)) >> 16;   // RTNE
    return (ushort_t)r;
}
__device__ inline float bf_lo(uint_t u) { return __uint_as_float(u << 16); }
__device__ inline float bf_hi(uint_t u) { return __uint_as_float(u & 0xffff0000u); }

#define PART_CHUNK 8192   // edges per block in k_cnt / k_part

// ---------------- CSR build: counting sort ----------------

__global__ __launch_bounds__(256) void k_cnt(const int* __restrict__ ei, int* __restrict__ tot, int E, int NB) {
    __shared__ int h[512];
    int tid = threadIdx.x;
    for (int b = tid; b < NB; b += 256) h[b] = 0;
    __syncthreads();
    int b0 = blockIdx.x * PART_CHUNK;
    int b1 = min(b0 + PART_CHUNK, E);
    for (int j = b0 + tid; j < b1; j += 256) atomicAdd(&h[ei[E + j] >> 8], 1);
    __syncthreads();
    for (int b = tid; b < NB; b += 256) if (h[b]) atomicAdd(&tot[b], h[b]);
}

__global__ __launch_bounds__(256) void k_scan(const int* __restrict__ tot, int* __restrict__ base,
                                              int* __restrict__ gofs, int* __restrict__ rowptr,
                                              int NB, int E, int N) {
    __shared__ int t[256];
    int tid = threadIdx.x;
    int v0 = (2 * tid < NB) ? tot[2 * tid] : 0;
    int v1 = (2 * tid + 1 < NB) ? tot[2 * tid + 1] : 0;
    t[tid] = v0 + v1;
    __syncthreads();
    for (int off = 1; off < 256; off <<= 1) {
        int u = (tid >= off) ? t[tid - off] : 0;
        __syncthreads();
        t[tid] += u;
        __syncthreads();
    }
    int pairExcl = (tid > 0) ? t[tid - 1] : 0;
    if (2 * tid < NB)     { base[2 * tid] = pairExcl;          gofs[2 * tid] = pairExcl; }
    if (2 * tid + 1 < NB) { base[2 * tid + 1] = pairExcl + v0; gofs[2 * tid + 1] = pairExcl + v0; }
    if (tid == 0) { rowptr[N] = E; base[NB] = E; }
}

// partition: pack (src | (dst&255)<<24) into bucket-contiguous order (N < 2^24)
__global__ __launch_bounds__(256) void k_part(const int* __restrict__ ei, int* __restrict__ gofs,
                                              uint_t* __restrict__ pairs, int E, int NB) {
    __shared__ int h[512];
    __shared__ int ofs[512];
    int tid = threadIdx.x;
    for (int b = tid; b < NB; b += 256) h[b] = 0;
    __syncthreads();
    int b0 = blockIdx.x * PART_CHUNK;
    int b1 = min(b0 + PART_CHUNK, E);
    for (int j = b0 + tid; j < b1; j += 256) atomicAdd(&h[ei[E + j] >> 8], 1);
    __syncthreads();
    for (int b = tid; b < NB; b += 256) ofs[b] = h[b] ? atomicAdd(&gofs[b], h[b]) : 0;
    __syncthreads();
    for (int j = b0 + tid; j < b1; j += 256) {
        int d = ei[E + j], s = ei[j];
        int p = atomicAdd(&ofs[d >> 8], 1);
        pairs[p] = (uint_t)s | ((uint_t)(d & 255) << 24);
    }
}

__global__ __launch_bounds__(256) void k_csr(const uint_t* __restrict__ pairs, const int* __restrict__ base,
                                             int* __restrict__ rowptr, int* __restrict__ csr, int N) {
    __shared__ int h[256];
    __shared__ int s[256];
    int b = blockIdx.x;
    int d0 = b << 8;
    int e0 = base[b], e1 = base[b + 1];
    int tid = threadIdx.x;
    h[tid] = 0;
    __syncthreads();
    for (int j = e0 + tid; j < e1; j += 256) atomicAdd(&h[pairs[j] >> 24], 1);
    __syncthreads();
    int v = h[tid];
    s[tid] = v;
    __syncthreads();
    for (int off = 1; off < 256; off <<= 1) {
        int u = (tid >= off) ? s[tid - off] : 0;
        __syncthreads();
        s[tid] += u;
        __syncthreads();
    }
    int excl = s[tid] - v;
    int d = d0 + tid;
    if (d < N) rowptr[d] = e0 + excl;
    __syncthreads();
    h[tid] = e0 + excl;
    __syncthreads();
    for (int j = e0 + tid; j < e1; j += 256) {
        uint_t p = pairs[j];
        int pos = atomicAdd(&h[p >> 24], 1);
        csr[pos] = (int)(p & 0xffffffu);
    }
}

// ---------------- x -> bf16 copy ----------------

__global__ __launch_bounds__(256) void k_cvt(const float* __restrict__ x, ushort_t* __restrict__ xh, int n4) {
    int idx = blockIdx.x * 256 + threadIdx.x;
    if (idx < n4) {
        float4 v = ((const float4*)x)[idx];
        ushort4 o = { f2bf(v.x), f2bf(v.y), f2bf(v.z), f2bf(v.w) };
        ((ushort4*)xh)[idx] = o;
    }
}

// ---------------- SAGE mean aggregation ----------------
// 16-lane group per node (4 nodes/wave). Lane l owns channels 4l..4l+3.
// Inner loop: macro-unrolled 16, ds_swizzle group-broadcast of row byte-offset.
// swizzle pattern (t<<5)|0x10: src_lane = (lane & 0x10) | t  (16-group bcast)

__global__ __launch_bounds__(256) void k_gather(const ushort_t* __restrict__ xh, const int* __restrict__ rowptr,
                                                const int* __restrict__ csr, ushort_t* __restrict__ aggh, int N) {
    int tid = threadIdx.x;
    int l = tid & 15;
    int i = blockIdx.x * 16 + (tid >> 4);
    if (i >= N) return;
    int r0 = rowptr[i], r1 = rowptr[i + 1];
    int deg = r1 - r0;
    const char* xb = (const char*)xh + l * 8;
    float a0 = 0.f, a1 = 0.f, a2 = 0.f, a3 = 0.f;
    int base = r0;

#define GSTEP(t) { \
        int off = __builtin_amdgcn_ds_swizzle(off_l, ((t) << 5) | 0x10); \
        uint2 u = *(const uint2*)(xb + off); \
        a0 += bf_lo(u.x); a1 += bf_hi(u.x); \
        a2 += bf_lo(u.y); a3 += bf_hi(u.y); }
#define GSTEPP(t) { \
        int off = __builtin_amdgcn_ds_swizzle(off_l, ((t) << 5) | 0x10); \
        if ((t) < cnt) { \
            uint2 u = *(const uint2*)(xb + off); \
            a0 += bf_lo(u.x); a1 += bf_hi(u.x); \
            a2 += bf_lo(u.y); a3 += bf_hi(u.y); } }

    for (; base + 16 <= r1; base += 16) {          // full chunks, no predication
        int off_l = csr[base + l] << 7;            // row byte offset (128 B rows)
        GSTEP(0)  GSTEP(1)  GSTEP(2)  GSTEP(3)
        GSTEP(4)  GSTEP(5)  GSTEP(6)  GSTEP(7)
        GSTEP(8)  GSTEP(9)  GSTEP(10) GSTEP(11)
        GSTEP(12) GSTEP(13) GSTEP(14) GSTEP(15)
    }
    int cnt = r1 - base;
    if (cnt > 0) {                                  // tail chunk, predicated
        int off_l = ((l < cnt) ? csr[base + l] : csr[base]) << 7;
        GSTEPP(0)  GSTEPP(1)  GSTEPP(2)  GSTEPP(3)
        GSTEPP(4)  GSTEPP(5)  GSTEPP(6)  GSTEPP(7)
        GSTEPP(8)  GSTEPP(9)  GSTEPP(10) GSTEPP(11)
        GSTEPP(12) GSTEPP(13) GSTEPP(14) GSTEPP(15)
    }
#undef GSTEP
#undef GSTEPP
    float dn = 1.0f / fmaxf((float)deg, 1.0f);
    ushort4 o = { f2bf(a0 * dn), f2bf(a1 * dn), f2bf(a2 * dn), f2bf(a3 * dn) };
    *(ushort4*)(aggh + (size_t)i * 64 + l * 4) = o;
}

// ---------------- Fused node GEMMs + attention scores ----------------
// h = relu(agg@Wl + x@Wr + b1); z = h@Wg (bf16); a_s = z.att_src; a_d = z.att_dst

__global__ __launch_bounds__(256) void k_gemm(const ushort_t* __restrict__ aggh, const float* __restrict__ x,
                                              const float* __restrict__ Wl, const float* __restrict__ Wr,
                                              const float* __restrict__ b1, const float* __restrict__ Wg,
                                              const float* __restrict__ att_src, const float* __restrict__ att_dst,
                                              ushort_t* __restrict__ zh, float* __restrict__ a_s,
                                              float* __restrict__ a_d, int N) {
    __shared__ alignas(16) float Ws[128 * 64];
    __shared__ alignas(16) float Wgs[64 * 32];
    __shared__ alignas(16) float As[64 * 68];
    int tid = threadIdx.x;
    for (int i = tid; i < 64 * 64; i += 256) { Ws[i] = Wl[i]; Ws[64 * 64 + i] = Wr[i]; }
    for (int i = tid; i < 64 * 32; i += 256) Wgs[i] = Wg[i];
    int m0 = blockIdx.x * 64;
    int tx = tid & 15, ty = tid >> 4;

    float acc[4][4] = {};
    for (int p = 0; p < 2; ++p) {
        __syncthreads();
        #pragma unroll
        for (int l = 0; l < 4; ++l) {
            int idx = tid + l * 256;
            int m = idx >> 4, kq = idx & 15;
            float4 v = { 0.f, 0.f, 0.f, 0.f };
            if (m0 + m < N) {
                if (p == 0) {
                    uint2 u = *(const uint2*)(aggh + (size_t)(m0 + m) * 64 + kq * 4);
                    v.x = bf_lo(u.x); v.y = bf_hi(u.x); v.z = bf_lo(u.y); v.w = bf_hi(u.y);
                } else {
                    v = *(const float4*)(x + (size_t)(m0 + m) * 64 + kq * 4);
                }
            }
            As[(kq * 4 + 0) * 68 + m] = v.x;
            As[(kq * 4 + 1) * 68 + m] = v.y;
            As[(kq * 4 + 2) * 68 + m] = v.z;
            As[(kq * 4 + 3) * 68 + m] = v.w;
        }
        __syncthreads();
        const float* wbase = Ws + p * 64 * 64;
        #pragma unroll 8
        for (int k = 0; k < 64; ++k) {
            float4 a = *(const float4*)&As[k * 68 + ty * 4];
            float4 b = *(const float4*)&wbase[k * 64 + tx * 4];
            acc[0][0] += a.x * b.x; acc[0][1] += a.x * b.y; acc[0][2] += a.x * b.z; acc[0][3] += a.x * b.w;
            acc[1][0] += a.y * b.x; acc[1][1] += a.y * b.y; acc[1][2] += a.y * b.z; acc[1][3] += a.y * b.w;
            acc[2][0] += a.z * b.x; acc[2][1] += a.z * b.y; acc[2][2] += a.z * b.z; acc[2][3] += a.z * b.w;
            acc[3][0] += a.w * b.x; acc[3][1] += a.w * b.y; acc[3][2] += a.w * b.z; acc[3][3] += a.w * b.w;
        }
    }
    __syncthreads();
    #pragma unroll
    for (int r = 0; r < 4; ++r)
        #pragma unroll
        for (int c = 0; c < 4; ++c) {
            float h = acc[r][c] + b1[tx * 4 + c];
            As[(tx * 4 + c) * 68 + ty * 4 + r] = fmaxf(h, 0.f);
        }
    __syncthreads();
    float acc2[4][2] = {};
    #pragma unroll 8
    for (int k = 0; k < 64; ++k) {
        float4 a = *(const float4*)&As[k * 68 + ty * 4];
        float g0 = Wgs[k * 32 + tx * 2], g1 = Wgs[k * 32 + tx * 2 + 1];
        acc2[0][0] += a.x * g0; acc2[0][1] += a.x * g1;
        acc2[1][0] += a.y * g0; acc2[1][1] += a.y * g1;
        acc2[2][0] += a.z * g0; acc2[2][1] += a.z * g1;
        acc2[3][0] += a.w * g0; acc2[3][1] += a.w * g1;
    }
    float as0 = att_src[tx * 2], as1 = att_src[tx * 2 + 1];
    float ad0 = att_dst[tx * 2], ad1 = att_dst[tx * 2 + 1];
    #pragma unroll
    for (int r = 0; r < 4; ++r) {
        int m = m0 + ty * 4 + r;
        float z0 = acc2[r][0], z1 = acc2[r][1];
        float ps = z0 * as0 + z1 * as1;
        float pd = z0 * ad0 + z1 * ad1;
        #pragma unroll
        for (int off = 8; off; off >>= 1) {
            ps += __shfl_xor(ps, off, 64);
            pd += __shfl_xor(pd, off, 64);
        }
        if (m < N) {
            ushort2 zz = { f2bf(z0), f2bf(z1) };
            *(ushort2*)(zh + (size_t)m * 32 + tx * 2) = zz;
            if (tx == 0) { a_s[m] = ps; a_d[m] = pd; }
        }
    }
}

// ---------------- GAT softmax aggregation + bias + log_softmax ----------------
// 16-lane group per node. Lane l owns channels 2l, 2l+1. No max subtraction
// (scores bounded, softmax shift-invariant; validated rounds 1-3).

__global__ __launch_bounds__(256) void k_gat(const ushort_t* __restrict__ zh, const float* __restrict__ a_s,
                                             const float* __restrict__ a_d, const int* __restrict__ rowptr,
                                             const int* __restrict__ csr, const float* __restrict__ b2,
                                             float* __restrict__ out, int N) {
    int tid = threadIdx.x;
    int l = tid & 15;
    int i = blockIdx.x * 16 + (tid >> 4);
    if (i >= N) return;
    int r0 = rowptr[i], r1 = rowptr[i + 1];
    float adi = a_d[i], asi = a_s[i];
    const char* zb = (const char*)zh + l * 4;
    float accx = 0.f, accy = 0.f, dsum = 0.f;
    int base = r0;

#define ASTEP(t) { \
        int off = __builtin_amdgcn_ds_swizzle(off_l, ((t) << 5) | 0x10); \
        float w = __int_as_float(__builtin_amdgcn_ds_swizzle(__float_as_int(w_l), ((t) << 5) | 0x10)); \
        uint_t u = *(const uint_t*)(zb + off); \
        accx += w * bf_lo(u); \
        accy += w * bf_hi(u); }
#define ASTEPP(t) { \
        int off = __builtin_amdgcn_ds_swizzle(off_l, ((t) << 5) | 0x10); \
        float w = __int_as_float(__builtin_amdgcn_ds_swizzle(__float_as_int(w_l), ((t) << 5) | 0x10)); \
        if ((t) < cnt) { \
            uint_t u = *(const uint_t*)(zb + off); \
            accx += w * bf_lo(u); \
            accy += w * bf_hi(u); } }

    for (; base + 16 <= r1; base += 16) {          // full chunks
        int s_l = csr[base + l];
        float e = a_s[s_l] + adi;
        e = fmaxf(e, 0.2f * e);                     // leaky_relu
        float w_l = __expf(e);
        dsum += w_l;
        int off_l = s_l << 6;                       // z row byte offset (64 B)
        ASTEP(0)  ASTEP(1)  ASTEP(2)  ASTEP(3)
        ASTEP(4)  ASTEP(5)  ASTEP(6)  ASTEP(7)
        ASTEP(8)  ASTEP(9)  ASTEP(10) ASTEP(11)
        ASTEP(12) ASTEP(13) ASTEP(14) ASTEP(15)
    }
    int cnt = r1 - base;
    if (cnt > 0) {                                  // tail chunk
        int s_l = (l < cnt) ? csr[base + l] : csr[base];
        float w_l = 0.f;
        if (l < cnt) {
            float e = a_s[s_l] + adi;
            e = fmaxf(e, 0.2f * e);
            w_l = __expf(e);
            dsum += w_l;
        }
        int off_l = s_l << 6;
        ASTEPP(0)  ASTEPP(1)  ASTEPP(2)  ASTEPP(3)
        ASTEPP(4)  ASTEPP(5)  ASTEPP(6)  ASTEPP(7)
        ASTEPP(8)  ASTEPP(9)  ASTEPP(10) ASTEPP(11)
        ASTEPP(12) ASTEPP(13) ASTEPP(14) ASTEPP(15)
    }
#undef ASTEP
#undef ASTEPP
    // in-group reductions (16 lanes)
    #pragma unroll
    for (int off = 8; off; off >>= 1) dsum += __shfl_xor(dsum, off, 64);
    // self loop
    float es = asi + adi; es = fmaxf(es, 0.2f * es);
    float wse = __expf(es);
    float denom = dsum + wse;
    uint_t us = *(const uint_t*)((const char*)zh + (size_t)i * 64 + l * 4);
    accx += wse * bf_lo(us);
    accy += wse * bf_hi(us);

    float rden = 1.0f / denom;
    float o0 = accx * rden + b2[l * 2];
    float o1 = accy * rden + b2[l * 2 + 1];
    float m2 = fmaxf(o0, o1);
    #pragma unroll
    for (int off = 8; off; off >>= 1) m2 = fmaxf(m2, __shfl_xor(m2, off, 64));
    float ssum = __expf(o0 - m2) + __expf(o1 - m2);
    #pragma unroll
    for (int off = 8; off; off >>= 1) ssum += __shfl_xor(ssum, off, 64);
    float lg = m2 + __logf(ssum);
    float2 r = { o0 - lg, o1 - lg };
    *(float2*)(out + (size_t)i * 32 + l * 2) = r;
}

// ---------------- host launch ----------------

extern "C" void kernel_launch(void* const* d_in, const int* in_sizes, int n_in,
                              void* d_out, int out_size, void* d_ws, size_t ws_size,
                              hipStream_t stream) {
    const float* x       = (const float*)d_in[0];
    const int*   ei      = (const int*)d_in[1];
    const float* Wl      = (const float*)d_in[2];
    const float* Wr      = (const float*)d_in[3];
    const float* b1      = (const float*)d_in[4];
    const float* Wg      = (const float*)d_in[5];
    const float* att_src = (const float*)d_in[6];
    const float* att_dst = (const float*)d_in[7];
    const float* b2      = (const float*)d_in[8];
    float* out = (float*)d_out;

    int N = in_sizes[0] / 64;
    int E = in_sizes[1] / 2;
    int NB = (N + 255) >> 8;

    char* ws = (char*)d_ws;
    size_t off = 0;
    auto alloc = [&](size_t bytes) { size_t r = off; off += (bytes + 255) & ~(size_t)255; return r; };
    int* tot       = (int*)(ws + alloc((size_t)(NB + 1) * 4));
    int* base      = (int*)(ws + alloc((size_t)(NB + 1) * 4));
    int* gofs      = (int*)(ws + alloc((size_t)(NB + 1) * 4));
    int* rowptr    = (int*)(ws + alloc((size_t)(N + 1) * 4));
    uint_t* pairs  = (uint_t*)(ws + alloc((size_t)E * 4));
    int* csr       = (int*)(ws + alloc((size_t)E * 4));
    ushort_t* xh   = (ushort_t*)(ws + alloc((size_t)N * 64 * 2));
    ushort_t* aggh = (ushort_t*)(ws + alloc((size_t)N * 64 * 2));
    ushort_t* zh   = (ushort_t*)(ws + alloc((size_t)N * 32 * 2));
    float* a_s     = (float*)(ws + alloc((size_t)N * 4));
    float* a_d     = (float*)(ws + alloc((size_t)N * 4));

    (void)hipMemsetAsync(tot, 0, (size_t)NB * 4, stream);

    int nchunk = (E + PART_CHUNK - 1) / PART_CHUNK;
    int n4 = N * 64 / 4;
    k_cnt    <<<nchunk, 256, 0, stream>>>(ei, tot, E, NB);
    k_cvt    <<<(n4 + 255) / 256, 256, 0, stream>>>(x, xh, n4);
    k_scan   <<<1, 256, 0, stream>>>(tot, base, gofs, rowptr, NB, E, N);
    k_part   <<<nchunk, 256, 0, stream>>>(ei, gofs, pairs, E, NB);
    k_csr    <<<NB, 256, 0, stream>>>(pairs, base, rowptr, csr, N);
    k_gather <<<(N + 15) / 16, 256, 0, stream>>>(xh, rowptr, csr, aggh, N);
    k_gemm   <<<(N + 63) / 64, 256, 0, stream>>>(aggh, x, Wl, Wr, b1, Wg, att_src, att_dst, zh, a_s, a_d, N);
    k_gat    <<<(N + 15) / 16, 256, 0, stream>>>(zh, a_s, a_d, rowptr, csr, b2, out, N);
}

// Round 6
// 250.443 us; speedup vs baseline: 2.0165x; 1.1393x over previous
//
#include <hip/hip_runtime.h>
#include <cstdint>
#include <cstddef>

// GNN: SAGEConv(mean) + GATConv(1 head, self-loops) + log_softmax
// CSR via two-level counting sort. 16-lane-group aggregation kernels with
// ds_swizzle broadcast. Node GEMMs on MFMA (bf16 in, fp32 acc).

typedef unsigned short ushort_t;
typedef unsigned int uint_t;
typedef __attribute__((ext_vector_type(8))) short short8;
typedef __attribute__((ext_vector_type(4))) float f32x4;

__device__ inline ushort_t f2bf(float f) {
    uint_t u = __float_as_uint(f);
    uint_t r = (u + 0x7fffu + ((u >> 16) & 1u)) >> 16;   // RTNE
    return (ushort_t)r;
}
__device__ inline float bf_lo(uint_t u) { return __uint_as_float(u << 16); }
__device__ inline float bf_hi(uint_t u) { return __uint_as_float(u & 0xffff0000u); }

#define PART_CHUNK 8192   // edges per block in k_cnt / k_part

// ---------------- CSR build: counting sort ----------------

__global__ __launch_bounds__(256) void k_cnt(const int* __restrict__ ei, int* __restrict__ tot, int E, int NB) {
    __shared__ int h[512];
    int tid = threadIdx.x;
    for (int b = tid; b < NB; b += 256) h[b] = 0;
    __syncthreads();
    int b0 = blockIdx.x * PART_CHUNK;
    int b1 = min(b0 + PART_CHUNK, E);
    for (int j = b0 + tid; j < b1; j += 256) atomicAdd(&h[ei[E + j] >> 8], 1);
    __syncthreads();
    for (int b = tid; b < NB; b += 256) if (h[b]) atomicAdd(&tot[b], h[b]);
}

__global__ __launch_bounds__(256) void k_scan(const int* __restrict__ tot, int* __restrict__ base,
                                              int* __restrict__ gofs, int* __restrict__ rowptr,
                                              int NB, int E, int N) {
    __shared__ int t[256];
    int tid = threadIdx.x;
    int v0 = (2 * tid < NB) ? tot[2 * tid] : 0;
    int v1 = (2 * tid + 1 < NB) ? tot[2 * tid + 1] : 0;
    t[tid] = v0 + v1;
    __syncthreads();
    for (int off = 1; off < 256; off <<= 1) {
        int u = (tid >= off) ? t[tid - off] : 0;
        __syncthreads();
        t[tid] += u;
        __syncthreads();
    }
    int pairExcl = (tid > 0) ? t[tid - 1] : 0;
    if (2 * tid < NB)     { base[2 * tid] = pairExcl;          gofs[2 * tid] = pairExcl; }
    if (2 * tid + 1 < NB) { base[2 * tid + 1] = pairExcl + v0; gofs[2 * tid + 1] = pairExcl + v0; }
    if (tid == 0) { rowptr[N] = E; base[NB] = E; }
}

// partition: pack (src | (dst&255)<<24) into bucket-contiguous order (N < 2^24)
__global__ __launch_bounds__(256) void k_part(const int* __restrict__ ei, int* __restrict__ gofs,
                                              uint_t* __restrict__ pairs, int E, int NB) {
    __shared__ int h[512];
    __shared__ int ofs[512];
    int tid = threadIdx.x;
    for (int b = tid; b < NB; b += 256) h[b] = 0;
    __syncthreads();
    int b0 = blockIdx.x * PART_CHUNK;
    int b1 = min(b0 + PART_CHUNK, E);
    for (int j = b0 + tid; j < b1; j += 256) atomicAdd(&h[ei[E + j] >> 8], 1);
    __syncthreads();
    for (int b = tid; b < NB; b += 256) ofs[b] = h[b] ? atomicAdd(&gofs[b], h[b]) : 0;
    __syncthreads();
    for (int j = b0 + tid; j < b1; j += 256) {
        int d = ei[E + j], s = ei[j];
        int p = atomicAdd(&ofs[d >> 8], 1);
        pairs[p] = (uint_t)s | ((uint_t)(d & 255) << 24);
    }
}

__global__ __launch_bounds__(256) void k_csr(const uint_t* __restrict__ pairs, const int* __restrict__ base,
                                             int* __restrict__ rowptr, int* __restrict__ csr, int N) {
    __shared__ int h[256];
    __shared__ int s[256];
    int b = blockIdx.x;
    int d0 = b << 8;
    int e0 = base[b], e1 = base[b + 1];
    int tid = threadIdx.x;
    h[tid] = 0;
    __syncthreads();
    for (int j = e0 + tid; j < e1; j += 256) atomicAdd(&h[pairs[j] >> 24], 1);
    __syncthreads();
    int v = h[tid];
    s[tid] = v;
    __syncthreads();
    for (int off = 1; off < 256; off <<= 1) {
        int u = (tid >= off) ? s[tid - off] : 0;
        __syncthreads();
        s[tid] += u;
        __syncthreads();
    }
    int excl = s[tid] - v;
    int d = d0 + tid;
    if (d < N) rowptr[d] = e0 + excl;
    __syncthreads();
    h[tid] = e0 + excl;
    __syncthreads();
    for (int j = e0 + tid; j < e1; j += 256) {
        uint_t p = pairs[j];
        int pos = atomicAdd(&h[p >> 24], 1);
        csr[pos] = (int)(p & 0xffffffu);
    }
}

// ---------------- x -> bf16 copy ----------------

__global__ __launch_bounds__(256) void k_cvt(const float* __restrict__ x, ushort_t* __restrict__ xh, int n4) {
    int idx = blockIdx.x * 256 + threadIdx.x;
    if (idx < n4) {
        float4 v = ((const float4*)x)[idx];
        ushort4 o = { f2bf(v.x), f2bf(v.y), f2bf(v.z), f2bf(v.w) };
        ((ushort4*)xh)[idx] = o;
    }
}

// weights -> bf16, transposed to [n][k] so B-frag k-runs are contiguous
__global__ __launch_bounds__(256) void k_wcvt(const float* __restrict__ Wl, const float* __restrict__ Wr,
                                              const float* __restrict__ Wg,
                                              ushort_t* __restrict__ Wlrt, ushort_t* __restrict__ Wgt) {
    int t = blockIdx.x * 256 + threadIdx.x;
    if (t < 64 * 128) {           // Wlrt[n][k], k<64 -> Wl[k][n], k>=64 -> Wr[k-64][n]
        int n = t >> 7, k = t & 127;
        float v = (k < 64) ? Wl[k * 64 + n] : Wr[(k - 64) * 64 + n];
        Wlrt[n * 128 + k] = f2bf(v);
    }
    if (t < 32 * 64) {            // Wgt[n][k] = Wg[k][n]
        int n = t >> 6, k = t & 63;
        Wgt[n * 64 + k] = f2bf(Wg[k * 32 + n]);
    }
}

// ---------------- SAGE mean aggregation ----------------

__global__ __launch_bounds__(256) void k_gather(const ushort_t* __restrict__ xh, const int* __restrict__ rowptr,
                                                const int* __restrict__ csr, ushort_t* __restrict__ aggh, int N) {
    int tid = threadIdx.x;
    int l = tid & 15;
    int i = blockIdx.x * 16 + (tid >> 4);
    if (i >= N) return;
    int r0 = rowptr[i], r1 = rowptr[i + 1];
    int deg = r1 - r0;
    const char* xb = (const char*)xh + l * 8;
    float a0 = 0.f, a1 = 0.f, a2 = 0.f, a3 = 0.f;
    int base = r0;

#define GSTEP(t) { \
        int off = __builtin_amdgcn_ds_swizzle(off_l, ((t) << 5) | 0x10); \
        uint2 u = *(const uint2*)(xb + off); \
        a0 += bf_lo(u.x); a1 += bf_hi(u.x); \
        a2 += bf_lo(u.y); a3 += bf_hi(u.y); }
#define GSTEPP(t) { \
        int off = __builtin_amdgcn_ds_swizzle(off_l, ((t) << 5) | 0x10); \
        if ((t) < cnt) { \
            uint2 u = *(const uint2*)(xb + off); \
            a0 += bf_lo(u.x); a1 += bf_hi(u.x); \
            a2 += bf_lo(u.y); a3 += bf_hi(u.y); } }

    for (; base + 16 <= r1; base += 16) {
        int off_l = csr[base + l] << 7;
        GSTEP(0)  GSTEP(1)  GSTEP(2)  GSTEP(3)
        GSTEP(4)  GSTEP(5)  GSTEP(6)  GSTEP(7)
        GSTEP(8)  GSTEP(9)  GSTEP(10) GSTEP(11)
        GSTEP(12) GSTEP(13) GSTEP(14) GSTEP(15)
    }
    int cnt = r1 - base;
    if (cnt > 0) {
        int off_l = ((l < cnt) ? csr[base + l] : csr[base]) << 7;
        GSTEPP(0)  GSTEPP(1)  GSTEPP(2)  GSTEPP(3)
        GSTEPP(4)  GSTEPP(5)  GSTEPP(6)  GSTEPP(7)
        GSTEPP(8)  GSTEPP(9)  GSTEPP(10) GSTEPP(11)
        GSTEPP(12) GSTEPP(13) GSTEPP(14) GSTEPP(15)
    }
#undef GSTEP
#undef GSTEPP
    float dn = 1.0f / fmaxf((float)deg, 1.0f);
    ushort4 o = { f2bf(a0 * dn), f2bf(a1 * dn), f2bf(a2 * dn), f2bf(a3 * dn) };
    *(ushort4*)(aggh + (size_t)i * 64 + l * 4) = o;
}

// ---------------- MFMA node GEMMs + attention scores ----------------
// h = relu([agg|x] @ [Wl;Wr] + b1)  (K=128, MFMA 16x16x32 bf16)
// z = h @ Wg (K=64); zh bf16; a_s = z.att_src; a_d = z.att_dst fused.
// Block: 64 rows, 4 waves x 16 rows. One __syncthreads (weight staging).

__global__ __launch_bounds__(256) void k_gemm(const ushort_t* __restrict__ aggh, const ushort_t* __restrict__ xh,
                                              const ushort_t* __restrict__ Wlrt, const ushort_t* __restrict__ Wgt,
                                              const float* __restrict__ b1,
                                              const float* __restrict__ att_src, const float* __restrict__ att_dst,
                                              ushort_t* __restrict__ zh, float* __restrict__ a_s,
                                              float* __restrict__ a_d, int N) {
    __shared__ ushort_t Wls[64 * 136];   // [n][k], padded row 136 (stride 68 dw -> 2-way, free)
    __shared__ ushort_t Wgs[32 * 72];    // [n][k], padded row 72  (stride 36 dw -> 2-way)
    __shared__ ushort_t hs[64 * 136];    // per-wave 16x136 h tiles
    int tid = threadIdx.x;
    for (int t = tid; t < 64 * 16; t += 256) {
        int n = t >> 4, cq = t & 15;
        *(uint4*)(&Wls[n * 136 + cq * 8]) = *(const uint4*)(&Wlrt[n * 128 + cq * 8]);
    }
    for (int t = tid; t < 32 * 8; t += 256) {
        int n = t >> 3, cq = t & 7;
        *(uint4*)(&Wgs[n * 72 + cq * 8]) = *(const uint4*)(&Wgt[n * 64 + cq * 8]);
    }
    __syncthreads();

    int w = tid >> 6, lane = tid & 63;
    int c = lane & 15, quad = lane >> 4;
    int m0 = blockIdx.x * 64 + w * 16;
    int row = m0 + c;                      // A-frag row for this lane
    bool rowok = row < N;

    // ---- phase 1: h = [agg|x] @ Wlr ----
    f32x4 acc[4] = {};
    #pragma unroll
    for (int kk = 0; kk < 4; ++kk) {
        const ushort_t* Abase = (kk < 2) ? aggh : xh;
        int koff = (kk & 1) * 32 + quad * 8;
        short8 a = {};
        if (rowok) a = *(const short8*)(Abase + (size_t)row * 64 + koff);
        #pragma unroll
        for (int nb = 0; nb < 4; ++nb) {
            short8 b = *(const short8*)(&Wls[(nb * 16 + c) * 136 + kk * 32 + quad * 8]);
            acc[nb] = __builtin_amdgcn_mfma_f32_16x16x32_bf16(a, b, acc[nb], 0, 0, 0);
        }
    }
    // ---- h epilogue: bias + relu -> per-wave LDS tile (bf16, [m][k]) ----
    ushort_t* hw = &hs[w * 16 * 136];
    #pragma unroll
    for (int nb = 0; nb < 4; ++nb) {
        float bb = b1[nb * 16 + c];
        #pragma unroll
        for (int r = 0; r < 4; ++r) {
            float h = acc[nb][r] + bb;
            hw[(quad * 4 + r) * 136 + nb * 16 + c] = f2bf(fmaxf(h, 0.f));
        }
    }
    // ---- phase 2: z = h @ Wg ----  (same-wave LDS dep, no barrier)
    f32x4 acc2[2] = {};
    #pragma unroll
    for (int kk = 0; kk < 2; ++kk) {
        short8 a = *(const short8*)(&hw[c * 136 + kk * 32 + quad * 8]);
        #pragma unroll
        for (int nb = 0; nb < 2; ++nb) {
            short8 b = *(const short8*)(&Wgs[(nb * 16 + c) * 72 + kk * 32 + quad * 8]);
            acc2[nb] = __builtin_amdgcn_mfma_f32_16x16x32_bf16(a, b, acc2[nb], 0, 0, 0);
        }
    }
    // ---- z epilogue: store zh + fused a_s/a_d ----
    float as0 = att_src[c], as1 = att_src[16 + c];
    float ad0 = att_dst[c], ad1 = att_dst[16 + c];
    #pragma unroll
    for (int r = 0; r < 4; ++r) {
        int grow = m0 + quad * 4 + r;
        float z0 = acc2[0][r], z1 = acc2[1][r];
        float ps = z0 * as0 + z1 * as1;
        float pd = z0 * ad0 + z1 * ad1;
        #pragma unroll
        for (int off = 8; off; off >>= 1) {
            ps += __shfl_xor(ps, off, 64);
            pd += __shfl_xor(pd, off, 64);
        }
        if (grow < N) {
            zh[(size_t)grow * 32 + c] = f2bf(z0);
            zh[(size_t)grow * 32 + 16 + c] = f2bf(z1);
            if (c == 0) { a_s[grow] = ps; a_d[grow] = pd; }
        }
    }
}

// ---------------- GAT softmax aggregation + bias + log_softmax ----------------

__global__ __launch_bounds__(256) void k_gat(const ushort_t* __restrict__ zh, const float* __restrict__ a_s,
                                             const float* __restrict__ a_d, const int* __restrict__ rowptr,
                                             const int* __restrict__ csr, const float* __restrict__ b2,
                                             float* __restrict__ out, int N) {
    int tid = threadIdx.x;
    int l = tid & 15;
    int i = blockIdx.x * 16 + (tid >> 4);
    if (i >= N) return;
    int r0 = rowptr[i], r1 = rowptr[i + 1];
    float adi = a_d[i], asi = a_s[i];
    const char* zb = (const char*)zh + l * 4;
    float accx = 0.f, accy = 0.f, dsum = 0.f;
    int base = r0;

#define ASTEP(t) { \
        int off = __builtin_amdgcn_ds_swizzle(off_l, ((t) << 5) | 0x10); \
        float w = __int_as_float(__builtin_amdgcn_ds_swizzle(__float_as_int(w_l), ((t) << 5) | 0x10)); \
        uint_t u = *(const uint_t*)(zb + off); \
        accx += w * bf_lo(u); \
        accy += w * bf_hi(u); }
#define ASTEPP(t) { \
        int off = __builtin_amdgcn_ds_swizzle(off_l, ((t) << 5) | 0x10); \
        float w = __int_as_float(__builtin_amdgcn_ds_swizzle(__float_as_int(w_l), ((t) << 5) | 0x10)); \
        if ((t) < cnt) { \
            uint_t u = *(const uint_t*)(zb + off); \
            accx += w * bf_lo(u); \
            accy += w * bf_hi(u); } }

    for (; base + 16 <= r1; base += 16) {
        int s_l = csr[base + l];
        float e = a_s[s_l] + adi;
        e = fmaxf(e, 0.2f * e);
        float w_l = __expf(e);
        dsum += w_l;
        int off_l = s_l << 6;
        ASTEP(0)  ASTEP(1)  ASTEP(2)  ASTEP(3)
        ASTEP(4)  ASTEP(5)  ASTEP(6)  ASTEP(7)
        ASTEP(8)  ASTEP(9)  ASTEP(10) ASTEP(11)
        ASTEP(12) ASTEP(13) ASTEP(14) ASTEP(15)
    }
    int cnt = r1 - base;
    if (cnt > 0) {
        int s_l = (l < cnt) ? csr[base + l] : csr[base];
        float w_l = 0.f;
        if (l < cnt) {
            float e = a_s[s_l] + adi;
            e = fmaxf(e, 0.2f * e);
            w_l = __expf(e);
            dsum += w_l;
        }
        int off_l = s_l << 6;
        ASTEPP(0)  ASTEPP(1)  ASTEPP(2)  ASTEPP(3)
        ASTEPP(4)  ASTEPP(5)  ASTEPP(6)  ASTEPP(7)
        ASTEPP(8)  ASTEPP(9)  ASTEPP(10) ASTEPP(11)
        ASTEPP(12) ASTEPP(13) ASTEPP(14) ASTEPP(15)
    }
#undef ASTEP
#undef ASTEPP
    #pragma unroll
    for (int off = 8; off; off >>= 1) dsum += __shfl_xor(dsum, off, 64);
    float es = asi + adi; es = fmaxf(es, 0.2f * es);
    float wse = __expf(es);
    float denom = dsum + wse;
    uint_t us = *(const uint_t*)((const char*)zh + (size_t)i * 64 + l * 4);
    accx += wse * bf_lo(us);
    accy += wse * bf_hi(us);

    float rden = 1.0f / denom;
    float o0 = accx * rden + b2[l * 2];
    float o1 = accy * rden + b2[l * 2 + 1];
    float m2 = fmaxf(o0, o1);
    #pragma unroll
    for (int off = 8; off; off >>= 1) m2 = fmaxf(m2, __shfl_xor(m2, off, 64));
    float ssum = __expf(o0 - m2) + __expf(o1 - m2);
    #pragma unroll
    for (int off = 8; off; off >>= 1) ssum += __shfl_xor(ssum, off, 64);
    float lg = m2 + __logf(ssum);
    float2 r = { o0 - lg, o1 - lg };
    *(float2*)(out + (size_t)i * 32 + l * 2) = r;
}

// ---------------- host launch ----------------

extern "C" void kernel_launch(void* const* d_in, const int* in_sizes, int n_in,
                              void* d_out, int out_size, void* d_ws, size_t ws_size,
                              hipStream_t stream) {
    const float* x       = (const float*)d_in[0];
    const int*   ei      = (const int*)d_in[1];
    const float* Wl      = (const float*)d_in[2];
    const float* Wr      = (const float*)d_in[3];
    const float* b1      = (const float*)d_in[4];
    const float* Wg      = (const float*)d_in[5];
    const float* att_src = (const float*)d_in[6];
    const float* att_dst = (const float*)d_in[7];
    const float* b2      = (const float*)d_in[8];
    float* out = (float*)d_out;

    int N = in_sizes[0] / 64;
    int E = in_sizes[1] / 2;
    int NB = (N + 255) >> 8;

    char* ws = (char*)d_ws;
    size_t off = 0;
    auto alloc = [&](size_t bytes) { size_t r = off; off += (bytes + 255) & ~(size_t)255; return r; };
    int* tot       = (int*)(ws + alloc((size_t)(NB + 1) * 4));
    int* base      = (int*)(ws + alloc((size_t)(NB + 1) * 4));
    int* gofs      = (int*)(ws + alloc((size_t)(NB + 1) * 4));
    int* rowptr    = (int*)(ws + alloc((size_t)(N + 1) * 4));
    uint_t* pairs  = (uint_t*)(ws + alloc((size_t)E * 4));
    int* csr       = (int*)(ws + alloc((size_t)E * 4));
    ushort_t* xh   = (ushort_t*)(ws + alloc((size_t)N * 64 * 2));
    ushort_t* aggh = (ushort_t*)(ws + alloc((size_t)N * 64 * 2));
    ushort_t* zh   = (ushort_t*)(ws + alloc((size_t)N * 32 * 2));
    float* a_s     = (float*)(ws + alloc((size_t)N * 4));
    float* a_d     = (float*)(ws + alloc((size_t)N * 4));
    ushort_t* Wlrt = (ushort_t*)(ws + alloc(64 * 128 * 2));
    ushort_t* Wgt  = (ushort_t*)(ws + alloc(32 * 64 * 2));

    (void)hipMemsetAsync(tot, 0, (size_t)NB * 4, stream);

    int nchunk = (E + PART_CHUNK - 1) / PART_CHUNK;
    int n4 = N * 64 / 4;
    k_cnt    <<<nchunk, 256, 0, stream>>>(ei, tot, E, NB);
    k_cvt    <<<(n4 + 255) / 256, 256, 0, stream>>>(x, xh, n4);
    k_wcvt   <<<32, 256, 0, stream>>>(Wl, Wr, Wg, Wlrt, Wgt);
    k_scan   <<<1, 256, 0, stream>>>(tot, base, gofs, rowptr, NB, E, N);
    k_part   <<<nchunk, 256, 0, stream>>>(ei, gofs, pairs, E, NB);
    k_csr    <<<NB, 256, 0, stream>>>(pairs, base, rowptr, csr, N);
    k_gather <<<(N + 15) / 16, 256, 0, stream>>>(xh, rowptr, csr, aggh, N);
    k_gemm   <<<(N + 63) / 64, 256, 0, stream>>>(aggh, xh, Wlrt, Wgt, b1, att_src, att_dst, zh, a_s, a_d, N);
    k_gat    <<<(N + 15) / 16, 256, 0, stream>>>(zh, a_s, a_d, rowptr, csr, b2, out, N);
}

// Round 7
// 229.583 us; speedup vs baseline: 2.1997x; 1.0909x over previous
//
#include <hip/hip_runtime.h>
#include <cstdint>
#include <cstddef>

// GNN: SAGEConv(mean) + GATConv(1 head, self-loops) + log_softmax
// CSR via two-level counting sort. 16-lane-group aggregation kernels with
// ds_swizzle broadcast; gathered operands compressed to fp8 e4m3 (HW cvt).
// Node GEMMs on MFMA (bf16 in, fp32 acc).

typedef unsigned short ushort_t;
typedef unsigned int uint_t;
typedef __attribute__((ext_vector_type(8))) short short8;
typedef __attribute__((ext_vector_type(4))) float f32x4;
typedef __attribute__((ext_vector_type(2))) float f32x2;

__device__ inline ushort_t f2bf(float f) {
    uint_t u = __float_as_uint(f);
    uint_t r = (u + 0x7fffu + ((u >> 16) & 1u)) >> 16;   // RTNE
    return (ushort_t)r;
}
__device__ inline float bf_lo(uint_t u) { return __uint_as_float(u << 16); }
__device__ inline float bf_hi(uint_t u) { return __uint_as_float(u & 0xffff0000u); }

#define PART_CHUNK 8192   // edges per block in k_cnt / k_part

// ---------------- CSR build: counting sort ----------------

__global__ __launch_bounds__(256) void k_cnt(const int* __restrict__ ei, int* __restrict__ tot, int E, int NB) {
    __shared__ int h[512];
    int tid = threadIdx.x;
    for (int b = tid; b < NB; b += 256) h[b] = 0;
    __syncthreads();
    int b0 = blockIdx.x * PART_CHUNK;
    int b1 = min(b0 + PART_CHUNK, E);
    for (int j = b0 + tid; j < b1; j += 256) atomicAdd(&h[ei[E + j] >> 8], 1);
    __syncthreads();
    for (int b = tid; b < NB; b += 256) if (h[b]) atomicAdd(&tot[b], h[b]);
}

__global__ __launch_bounds__(256) void k_scan(const int* __restrict__ tot, int* __restrict__ base,
                                              int* __restrict__ gofs, int* __restrict__ rowptr,
                                              int NB, int E, int N) {
    __shared__ int t[256];
    int tid = threadIdx.x;
    int v0 = (2 * tid < NB) ? tot[2 * tid] : 0;
    int v1 = (2 * tid + 1 < NB) ? tot[2 * tid + 1] : 0;
    t[tid] = v0 + v1;
    __syncthreads();
    for (int off = 1; off < 256; off <<= 1) {
        int u = (tid >= off) ? t[tid - off] : 0;
        __syncthreads();
        t[tid] += u;
        __syncthreads();
    }
    int pairExcl = (tid > 0) ? t[tid - 1] : 0;
    if (2 * tid < NB)     { base[2 * tid] = pairExcl;          gofs[2 * tid] = pairExcl; }
    if (2 * tid + 1 < NB) { base[2 * tid + 1] = pairExcl + v0; gofs[2 * tid + 1] = pairExcl + v0; }
    if (tid == 0) { rowptr[N] = E; base[NB] = E; }
}

// partition: pack (src | (dst&255)<<24) into bucket-contiguous order (N < 2^24)
__global__ __launch_bounds__(256) void k_part(const int* __restrict__ ei, int* __restrict__ gofs,
                                              uint_t* __restrict__ pairs, int E, int NB) {
    __shared__ int h[512];
    __shared__ int ofs[512];
    int tid = threadIdx.x;
    for (int b = tid; b < NB; b += 256) h[b] = 0;
    __syncthreads();
    int b0 = blockIdx.x * PART_CHUNK;
    int b1 = min(b0 + PART_CHUNK, E);
    for (int j = b0 + tid; j < b1; j += 256) atomicAdd(&h[ei[E + j] >> 8], 1);
    __syncthreads();
    for (int b = tid; b < NB; b += 256) ofs[b] = h[b] ? atomicAdd(&gofs[b], h[b]) : 0;
    __syncthreads();
    for (int j = b0 + tid; j < b1; j += 256) {
        int d = ei[E + j], s = ei[j];
        int p = atomicAdd(&ofs[d >> 8], 1);
        pairs[p] = (uint_t)s | ((uint_t)(d & 255) << 24);
    }
}

__global__ __launch_bounds__(256) void k_csr(const uint_t* __restrict__ pairs, const int* __restrict__ base,
                                             int* __restrict__ rowptr, int* __restrict__ csr, int N) {
    __shared__ int h[256];
    __shared__ int s[256];
    int b = blockIdx.x;
    int d0 = b << 8;
    int e0 = base[b], e1 = base[b + 1];
    int tid = threadIdx.x;
    h[tid] = 0;
    __syncthreads();
    for (int j = e0 + tid; j < e1; j += 256) atomicAdd(&h[pairs[j] >> 24], 1);
    __syncthreads();
    int v = h[tid];
    s[tid] = v;
    __syncthreads();
    for (int off = 1; off < 256; off <<= 1) {
        int u = (tid >= off) ? s[tid - off] : 0;
        __syncthreads();
        s[tid] += u;
        __syncthreads();
    }
    int excl = s[tid] - v;
    int d = d0 + tid;
    if (d < N) rowptr[d] = e0 + excl;
    __syncthreads();
    h[tid] = e0 + excl;
    __syncthreads();
    for (int j = e0 + tid; j < e1; j += 256) {
        uint_t p = pairs[j];
        int pos = atomicAdd(&h[p >> 24], 1);
        csr[pos] = (int)(p & 0xffffffu);
    }
}

// ---------------- x -> bf16 (for GEMM) + fp8 e4m3 (for gather) ----------------

__global__ __launch_bounds__(256) void k_cvt(const float* __restrict__ x, ushort_t* __restrict__ xh,
                                             unsigned char* __restrict__ xq, int n4) {
    int idx = blockIdx.x * 256 + threadIdx.x;
    if (idx < n4) {
        float4 v = ((const float4*)x)[idx];
        ushort4 o = { f2bf(v.x), f2bf(v.y), f2bf(v.z), f2bf(v.w) };
        ((ushort4*)xh)[idx] = o;
        int r = 0;
        r = __builtin_amdgcn_cvt_pk_fp8_f32(v.x, v.y, r, false);
        r = __builtin_amdgcn_cvt_pk_fp8_f32(v.z, v.w, r, true);
        ((uint_t*)xq)[idx] = (uint_t)r;
    }
}

// weights -> bf16, transposed to [n][k] so B-frag k-runs are contiguous
__global__ __launch_bounds__(256) void k_wcvt(const float* __restrict__ Wl, const float* __restrict__ Wr,
                                              const float* __restrict__ Wg,
                                              ushort_t* __restrict__ Wlrt, ushort_t* __restrict__ Wgt) {
    int t = blockIdx.x * 256 + threadIdx.x;
    if (t < 64 * 128) {
        int n = t >> 7, k = t & 127;
        float v = (k < 64) ? Wl[k * 64 + n] : Wr[(k - 64) * 64 + n];
        Wlrt[n * 128 + k] = f2bf(v);
    }
    if (t < 32 * 64) {
        int n = t >> 6, k = t & 63;
        Wgt[n * 64 + k] = f2bf(Wg[k * 32 + n]);
    }
}

// ---------------- SAGE mean aggregation (fp8 rows, 64 B) ----------------
// 16-lane group per node; lane l owns channels 4l..4l+3 (one uint load).

__global__ __launch_bounds__(256) void k_gather(const unsigned char* __restrict__ xq, const int* __restrict__ rowptr,
                                                const int* __restrict__ csr, ushort_t* __restrict__ aggh, int N) {
    int tid = threadIdx.x;
    int l = tid & 15;
    int i = blockIdx.x * 16 + (tid >> 4);
    if (i >= N) return;
    int r0 = rowptr[i], r1 = rowptr[i + 1];
    int deg = r1 - r0;
    const char* xb = (const char*)xq + l * 4;
    float a0 = 0.f, a1 = 0.f, a2 = 0.f, a3 = 0.f;
    int base = r0;

#define GSTEP(t) { \
        int off = __builtin_amdgcn_ds_swizzle(off_l, ((t) << 5) | 0x10); \
        uint_t u = *(const uint_t*)(xb + off); \
        f32x2 p0 = __builtin_amdgcn_cvt_pk_f32_fp8((int)u, false); \
        f32x2 p1 = __builtin_amdgcn_cvt_pk_f32_fp8((int)u, true); \
        a0 += p0.x; a1 += p0.y; a2 += p1.x; a3 += p1.y; }
#define GSTEPP(t) { \
        int off = __builtin_amdgcn_ds_swizzle(off_l, ((t) << 5) | 0x10); \
        if ((t) < cnt) { \
            uint_t u = *(const uint_t*)(xb + off); \
            f32x2 p0 = __builtin_amdgcn_cvt_pk_f32_fp8((int)u, false); \
            f32x2 p1 = __builtin_amdgcn_cvt_pk_f32_fp8((int)u, true); \
            a0 += p0.x; a1 += p0.y; a2 += p1.x; a3 += p1.y; } }

    for (; base + 16 <= r1; base += 16) {          // full chunks (64 B fp8 rows)
        int off_l = csr[base + l] << 6;
        GSTEP(0)  GSTEP(1)  GSTEP(2)  GSTEP(3)
        GSTEP(4)  GSTEP(5)  GSTEP(6)  GSTEP(7)
        GSTEP(8)  GSTEP(9)  GSTEP(10) GSTEP(11)
        GSTEP(12) GSTEP(13) GSTEP(14) GSTEP(15)
    }
    int cnt = r1 - base;
    if (cnt > 0) {
        int off_l = ((l < cnt) ? csr[base + l] : csr[base]) << 6;
        GSTEPP(0)  GSTEPP(1)  GSTEPP(2)  GSTEPP(3)
        GSTEPP(4)  GSTEPP(5)  GSTEPP(6)  GSTEPP(7)
        GSTEPP(8)  GSTEPP(9)  GSTEPP(10) GSTEPP(11)
        GSTEPP(12) GSTEPP(13) GSTEPP(14) GSTEPP(15)
    }
#undef GSTEP
#undef GSTEPP
    float dn = 1.0f / fmaxf((float)deg, 1.0f);
    ushort4 o = { f2bf(a0 * dn), f2bf(a1 * dn), f2bf(a2 * dn), f2bf(a3 * dn) };
    *(ushort4*)(aggh + (size_t)i * 64 + l * 4) = o;
}

// ---------------- MFMA node GEMMs + attention scores ----------------
// h = relu([agg|x] @ [Wl;Wr] + b1)  (K=128); z = h @ Wg (K=64).
// z stored fp8 e4m3 (zq); a_s/a_d fp32 exact from registers.

__global__ __launch_bounds__(256) void k_gemm(const ushort_t* __restrict__ aggh, const ushort_t* __restrict__ xh,
                                              const ushort_t* __restrict__ Wlrt, const ushort_t* __restrict__ Wgt,
                                              const float* __restrict__ b1,
                                              const float* __restrict__ att_src, const float* __restrict__ att_dst,
                                              unsigned char* __restrict__ zq, float* __restrict__ a_s,
                                              float* __restrict__ a_d, int N) {
    __shared__ ushort_t Wls[64 * 136];   // [n][k], stride 68 dw -> 2-way (free)
    __shared__ ushort_t Wgs[32 * 72];
    __shared__ ushort_t hs[64 * 136];    // per-wave 16x136 h tiles
    int tid = threadIdx.x;
    for (int t = tid; t < 64 * 16; t += 256) {
        int n = t >> 4, cq = t & 15;
        *(uint4*)(&Wls[n * 136 + cq * 8]) = *(const uint4*)(&Wlrt[n * 128 + cq * 8]);
    }
    for (int t = tid; t < 32 * 8; t += 256) {
        int n = t >> 3, cq = t & 7;
        *(uint4*)(&Wgs[n * 72 + cq * 8]) = *(const uint4*)(&Wgt[n * 64 + cq * 8]);
    }
    __syncthreads();

    int w = tid >> 6, lane = tid & 63;
    int c = lane & 15, quad = lane >> 4;
    int m0 = blockIdx.x * 64 + w * 16;
    int row = m0 + c;
    bool rowok = row < N;

    f32x4 acc[4] = {};
    #pragma unroll
    for (int kk = 0; kk < 4; ++kk) {
        const ushort_t* Abase = (kk < 2) ? aggh : xh;
        int koff = (kk & 1) * 32 + quad * 8;
        short8 a = {};
        if (rowok) a = *(const short8*)(Abase + (size_t)row * 64 + koff);
        #pragma unroll
        for (int nb = 0; nb < 4; ++nb) {
            short8 b = *(const short8*)(&Wls[(nb * 16 + c) * 136 + kk * 32 + quad * 8]);
            acc[nb] = __builtin_amdgcn_mfma_f32_16x16x32_bf16(a, b, acc[nb], 0, 0, 0);
        }
    }
    ushort_t* hw = &hs[w * 16 * 136];
    #pragma unroll
    for (int nb = 0; nb < 4; ++nb) {
        float bb = b1[nb * 16 + c];
        #pragma unroll
        for (int r = 0; r < 4; ++r) {
            float h = acc[nb][r] + bb;
            hw[(quad * 4 + r) * 136 + nb * 16 + c] = f2bf(fmaxf(h, 0.f));
        }
    }
    f32x4 acc2[2] = {};
    #pragma unroll
    for (int kk = 0; kk < 2; ++kk) {
        short8 a = *(const short8*)(&hw[c * 136 + kk * 32 + quad * 8]);
        #pragma unroll
        for (int nb = 0; nb < 2; ++nb) {
            short8 b = *(const short8*)(&Wgs[(nb * 16 + c) * 72 + kk * 32 + quad * 8]);
            acc2[nb] = __builtin_amdgcn_mfma_f32_16x16x32_bf16(a, b, acc2[nb], 0, 0, 0);
        }
    }
    float as0 = att_src[c], as1 = att_src[16 + c];
    float ad0 = att_dst[c], ad1 = att_dst[16 + c];
    #pragma unroll
    for (int r = 0; r < 4; ++r) {
        int grow = m0 + quad * 4 + r;
        float z0 = acc2[0][r], z1 = acc2[1][r];
        float ps = z0 * as0 + z1 * as1;
        float pd = z0 * ad0 + z1 * ad1;
        #pragma unroll
        for (int off = 8; off; off >>= 1) {
            ps += __shfl_xor(ps, off, 64);
            pd += __shfl_xor(pd, off, 64);
        }
        if (grow < N) {
            int r8 = __builtin_amdgcn_cvt_pk_fp8_f32(z0, z1, 0, false);
            unsigned char* zrow = zq + (size_t)grow * 32;
            zrow[c] = (unsigned char)(r8 & 0xff);
            zrow[16 + c] = (unsigned char)((r8 >> 8) & 0xff);
            if (c == 0) { a_s[grow] = ps; a_d[grow] = pd; }
        }
    }
}

// ---------------- GAT softmax aggregation + bias + log_softmax ----------------
// 16-lane group per node; lane l owns channels 2l,2l+1 (fp8 pair, 32 B rows).

__global__ __launch_bounds__(256) void k_gat(const unsigned char* __restrict__ zq, const float* __restrict__ a_s,
                                             const float* __restrict__ a_d, const int* __restrict__ rowptr,
                                             const int* __restrict__ csr, const float* __restrict__ b2,
                                             float* __restrict__ out, int N) {
    int tid = threadIdx.x;
    int l = tid & 15;
    int i = blockIdx.x * 16 + (tid >> 4);
    if (i >= N) return;
    int r0 = rowptr[i], r1 = rowptr[i + 1];
    float adi = a_d[i], asi = a_s[i];
    const char* zb = (const char*)zq + l * 2;
    float accx = 0.f, accy = 0.f, dsum = 0.f;
    int base = r0;

#define ASTEP(t) { \
        int off = __builtin_amdgcn_ds_swizzle(off_l, ((t) << 5) | 0x10); \
        float w = __int_as_float(__builtin_amdgcn_ds_swizzle(__float_as_int(w_l), ((t) << 5) | 0x10)); \
        uint_t u = *(const ushort_t*)(zb + off); \
        f32x2 p = __builtin_amdgcn_cvt_pk_f32_fp8((int)u, false); \
        accx += w * p.x; \
        accy += w * p.y; }
#define ASTEPP(t) { \
        int off = __builtin_amdgcn_ds_swizzle(off_l, ((t) << 5) | 0x10); \
        float w = __int_as_float(__builtin_amdgcn_ds_swizzle(__float_as_int(w_l), ((t) << 5) | 0x10)); \
        if ((t) < cnt) { \
            uint_t u = *(const ushort_t*)(zb + off); \
            f32x2 p = __builtin_amdgcn_cvt_pk_f32_fp8((int)u, false); \
            accx += w * p.x; \
            accy += w * p.y; } }

    for (; base + 16 <= r1; base += 16) {          // full chunks (32 B fp8 rows)
        int s_l = csr[base + l];
        float e = a_s[s_l] + adi;
        e = fmaxf(e, 0.2f * e);
        float w_l = __expf(e);
        dsum += w_l;
        int off_l = s_l << 5;
        ASTEP(0)  ASTEP(1)  ASTEP(2)  ASTEP(3)
        ASTEP(4)  ASTEP(5)  ASTEP(6)  ASTEP(7)
        ASTEP(8)  ASTEP(9)  ASTEP(10) ASTEP(11)
        ASTEP(12) ASTEP(13) ASTEP(14) ASTEP(15)
    }
    int cnt = r1 - base;
    if (cnt > 0) {
        int s_l = (l < cnt) ? csr[base + l] : csr[base];
        float w_l = 0.f;
        if (l < cnt) {
            float e = a_s[s_l] + adi;
            e = fmaxf(e, 0.2f * e);
            w_l = __expf(e);
            dsum += w_l;
        }
        int off_l = s_l << 5;
        ASTEPP(0)  ASTEPP(1)  ASTEPP(2)  ASTEPP(3)
        ASTEPP(4)  ASTEPP(5)  ASTEPP(6)  ASTEPP(7)
        ASTEPP(8)  ASTEPP(9)  ASTEPP(10) ASTEPP(11)
        ASTEPP(12) ASTEPP(13) ASTEPP(14) ASTEPP(15)
    }
#undef ASTEP
#undef ASTEPP
    #pragma unroll
    for (int off = 8; off; off >>= 1) dsum += __shfl_xor(dsum, off, 64);
    float es = asi + adi; es = fmaxf(es, 0.2f * es);
    float wse = __expf(es);
    float denom = dsum + wse;
    uint_t us = *(const ushort_t*)((const char*)zq + (size_t)i * 32 + l * 2);
    f32x2 pself = __builtin_amdgcn_cvt_pk_f32_fp8((int)us, false);
    accx += wse * pself.x;
    accy += wse * pself.y;

    float rden = 1.0f / denom;
    float o0 = accx * rden + b2[l * 2];
    float o1 = accy * rden + b2[l * 2 + 1];
    float m2 = fmaxf(o0, o1);
    #pragma unroll
    for (int off = 8; off; off >>= 1) m2 = fmaxf(m2, __shfl_xor(m2, off, 64));
    float ssum = __expf(o0 - m2) + __expf(o1 - m2);
    #pragma unroll
    for (int off = 8; off; off >>= 1) ssum += __shfl_xor(ssum, off, 64);
    float lg = m2 + __logf(ssum);
    float2 r = { o0 - lg, o1 - lg };
    *(float2*)(out + (size_t)i * 32 + l * 2) = r;
}

// ---------------- host launch ----------------

extern "C" void kernel_launch(void* const* d_in, const int* in_sizes, int n_in,
                              void* d_out, int out_size, void* d_ws, size_t ws_size,
                              hipStream_t stream) {
    const float* x       = (const float*)d_in[0];
    const int*   ei      = (const int*)d_in[1];
    const float* Wl      = (const float*)d_in[2];
    const float* Wr      = (const float*)d_in[3];
    const float* b1      = (const float*)d_in[4];
    const float* Wg      = (const float*)d_in[5];
    const float* att_src = (const float*)d_in[6];
    const float* att_dst = (const float*)d_in[7];
    const float* b2      = (const float*)d_in[8];
    float* out = (float*)d_out;

    int N = in_sizes[0] / 64;
    int E = in_sizes[1] / 2;
    int NB = (N + 255) >> 8;

    char* ws = (char*)d_ws;
    size_t off = 0;
    auto alloc = [&](size_t bytes) { size_t r = off; off += (bytes + 255) & ~(size_t)255; return r; };
    int* tot       = (int*)(ws + alloc((size_t)(NB + 1) * 4));
    int* base      = (int*)(ws + alloc((size_t)(NB + 1) * 4));
    int* gofs      = (int*)(ws + alloc((size_t)(NB + 1) * 4));
    int* rowptr    = (int*)(ws + alloc((size_t)(N + 1) * 4));
    uint_t* pairs  = (uint_t*)(ws + alloc((size_t)E * 4));
    int* csr       = (int*)(ws + alloc((size_t)E * 4));
    ushort_t* xh   = (ushort_t*)(ws + alloc((size_t)N * 64 * 2));
    unsigned char* xq = (unsigned char*)(ws + alloc((size_t)N * 64));
    ushort_t* aggh = (ushort_t*)(ws + alloc((size_t)N * 64 * 2));
    unsigned char* zq = (unsigned char*)(ws + alloc((size_t)N * 32));
    float* a_s     = (float*)(ws + alloc((size_t)N * 4));
    float* a_d     = (float*)(ws + alloc((size_t)N * 4));
    ushort_t* Wlrt = (ushort_t*)(ws + alloc(64 * 128 * 2));
    ushort_t* Wgt  = (ushort_t*)(ws + alloc(32 * 64 * 2));

    (void)hipMemsetAsync(tot, 0, (size_t)NB * 4, stream);

    int nchunk = (E + PART_CHUNK - 1) / PART_CHUNK;
    int n4 = N * 64 / 4;
    k_cnt    <<<nchunk, 256, 0, stream>>>(ei, tot, E, NB);
    k_cvt    <<<(n4 + 255) / 256, 256, 0, stream>>>(x, xh, xq, n4);
    k_wcvt   <<<32, 256, 0, stream>>>(Wl, Wr, Wg, Wlrt, Wgt);
    k_scan   <<<1, 256, 0, stream>>>(tot, base, gofs, rowptr, NB, E, N);
    k_part   <<<nchunk, 256, 0, stream>>>(ei, gofs, pairs, E, NB);
    k_csr    <<<NB, 256, 0, stream>>>(pairs, base, rowptr, csr, N);
    k_gather <<<(N + 15) / 16, 256, 0, stream>>>(xq, rowptr, csr, aggh, N);
    k_gemm   <<<(N + 63) / 64, 256, 0, stream>>>(aggh, xh, Wlrt, Wgt, b1, att_src, att_dst, zq, a_s, a_d, N);
    k_gat    <<<(N + 15) / 16, 256, 0, stream>>>(zq, a_s, a_d, rowptr, csr, b2, out, N);
}

// Round 8
// 210.660 us; speedup vs baseline: 2.3973x; 1.0898x over previous
//
#include <hip/hip_runtime.h>
#include <cstdint>
#include <cstddef>

// GNN: SAGEConv(mean) + GATConv(1 head, self-loops) + log_softmax
// CSR via two-level counting sort. Edge kernels: 16-lane-group per node,
// LDS-staged (offset,weight) broadcast, fp8 e4m3 compressed rows, zero-row
// padding for branchless tails. MFMA node GEMMs. 7 dispatches total.

typedef unsigned short ushort_t;
typedef unsigned int uint_t;
typedef __attribute__((ext_vector_type(8))) short short8;
typedef __attribute__((ext_vector_type(4))) float f32x4;
typedef __attribute__((ext_vector_type(2))) float f32x2;

__device__ inline ushort_t f2bf(float f) {
    uint_t u = __float_as_uint(f);
    uint_t r = (u + 0x7fffu + ((u >> 16) & 1u)) >> 16;   // RTNE
    return (ushort_t)r;
}

#define PART_CHUNK 8192   // edges per block in cnt / k_part

// ---------------- P0: cvt x -> bf16+fp8, weights -> bf16^T, bucket counts ----------------

__global__ __launch_bounds__(256) void k_pre(const float* __restrict__ x, ushort_t* __restrict__ xh,
                                             unsigned char* __restrict__ xq,
                                             const int* __restrict__ ei, int* __restrict__ tot,
                                             const float* __restrict__ Wl, const float* __restrict__ Wr,
                                             const float* __restrict__ Wg,
                                             ushort_t* __restrict__ Wlrt, ushort_t* __restrict__ Wgt,
                                             unsigned char* __restrict__ zq,
                                             int n4, int E, int NB, int N, int nchunk) {
    __shared__ int h[512];
    int bid = blockIdx.x, tid = threadIdx.x;
    int idx = bid * 256 + tid;
    if (idx < n4) {
        float4 v = ((const float4*)x)[idx];
        ushort4 o = { f2bf(v.x), f2bf(v.y), f2bf(v.z), f2bf(v.w) };
        ((ushort4*)xh)[idx] = o;
        int r = 0;
        r = __builtin_amdgcn_cvt_pk_fp8_f32(v.x, v.y, r, false);
        r = __builtin_amdgcn_cvt_pk_fp8_f32(v.z, v.w, r, true);
        ((uint_t*)xq)[idx] = (uint_t)r;
    }
    if (bid < nchunk) {                         // block-uniform branch: bucket histogram
        for (int b = tid; b < NB; b += 256) h[b] = 0;
        __syncthreads();
        int b0 = bid * PART_CHUNK;
        int b1 = min(b0 + PART_CHUNK, E);
        for (int j = b0 + tid; j < b1; j += 256) atomicAdd(&h[ei[E + j] >> 8], 1);
        __syncthreads();
        for (int b = tid; b < NB; b += 256) if (h[b]) atomicAdd(&tot[b], h[b]);
    } else if (bid == nchunk) {                 // zero rows (branchless tails elsewhere)
        if (tid < 16) ((uint_t*)(xq + (size_t)N * 64))[tid] = 0;
        if (tid < 8)  ((uint_t*)(zq + (size_t)N * 32))[tid] = 0;
    } else if (bid >= 512 && bid < 544) {       // weights -> bf16 transposed [n][k]
        int t = (bid - 512) * 256 + tid;        // 0..8191
        int n = t >> 7, k = t & 127;
        float v = (k < 64) ? Wl[k * 64 + n] : Wr[(k - 64) * 64 + n];
        Wlrt[n * 128 + k] = f2bf(v);
        if (t < 32 * 64) {
            int n2 = t >> 6, k2 = t & 63;
            Wgt[n2 * 64 + k2] = f2bf(Wg[k2 * 32 + n2]);
        }
    }
}

// ---------------- P1: exclusive scan of bucket totals ----------------

__global__ __launch_bounds__(256) void k_scan(const int* __restrict__ tot, int* __restrict__ base,
                                              int* __restrict__ gofs, int* __restrict__ rowptr,
                                              int NB, int E, int N) {
    __shared__ int t[256];
    int tid = threadIdx.x;
    int v0 = (2 * tid < NB) ? tot[2 * tid] : 0;
    int v1 = (2 * tid + 1 < NB) ? tot[2 * tid + 1] : 0;
    t[tid] = v0 + v1;
    __syncthreads();
    for (int off = 1; off < 256; off <<= 1) {
        int u = (tid >= off) ? t[tid - off] : 0;
        __syncthreads();
        t[tid] += u;
        __syncthreads();
    }
    int pairExcl = (tid > 0) ? t[tid - 1] : 0;
    if (2 * tid < NB)     { base[2 * tid] = pairExcl;          gofs[2 * tid] = pairExcl; }
    if (2 * tid + 1 < NB) { base[2 * tid + 1] = pairExcl + v0; gofs[2 * tid + 1] = pairExcl + v0; }
    if (tid == 0) { rowptr[N] = E; base[NB] = E; }
}

// ---------------- P2: partition (src | (dst&255)<<24) bucket-contiguous ----------------

__global__ __launch_bounds__(256) void k_part(const int* __restrict__ ei, int* __restrict__ gofs,
                                              uint_t* __restrict__ pairs, int E, int NB) {
    __shared__ int h[512];
    __shared__ int ofs[512];
    int tid = threadIdx.x;
    for (int b = tid; b < NB; b += 256) h[b] = 0;
    __syncthreads();
    int b0 = blockIdx.x * PART_CHUNK;
    int b1 = min(b0 + PART_CHUNK, E);
    for (int j = b0 + tid; j < b1; j += 256) atomicAdd(&h[ei[E + j] >> 8], 1);
    __syncthreads();
    for (int b = tid; b < NB; b += 256) ofs[b] = h[b] ? atomicAdd(&gofs[b], h[b]) : 0;
    __syncthreads();
    for (int j = b0 + tid; j < b1; j += 256) {
        int d = ei[E + j], s = ei[j];
        int p = atomicAdd(&ofs[d >> 8], 1);
        pairs[p] = (uint_t)s | ((uint_t)(d & 255) << 24);
    }
}

// ---------------- P3: per-bucket CSR build + fused SAGE gather ----------------
// Phase A: LDS degree count + scan -> rowptr, windowed csr scatter (L2-hot).
// Phase B: 16 groups x 16 passes gather fp8 x-rows, LDS-staged offsets.

__global__ __launch_bounds__(256) void k_csrg(const uint_t* __restrict__ pairs, const int* __restrict__ base,
                                              int* __restrict__ rowptr, int* __restrict__ csr,
                                              const unsigned char* __restrict__ xq,
                                              ushort_t* __restrict__ aggh, int N) {
    __shared__ int h[256];
    __shared__ int s[256];
    __shared__ int scr[256];
    int b = blockIdx.x;
    int d0 = b << 8;
    int e0 = base[b], e1 = base[b + 1];
    int tid = threadIdx.x;
    h[tid] = 0;
    __syncthreads();
    for (int j = e0 + tid; j < e1; j += 256) atomicAdd(&h[pairs[j] >> 24], 1);
    __syncthreads();
    int v = h[tid];
    s[tid] = v;
    __syncthreads();
    for (int off = 1; off < 256; off <<= 1) {
        int u = (tid >= off) ? s[tid - off] : 0;
        __syncthreads();
        s[tid] += u;
        __syncthreads();
    }
    int excl = s[tid] - v;
    if (d0 + tid < N) rowptr[d0 + tid] = e0 + excl;
    __syncthreads();
    h[tid] = e0 + excl;
    __syncthreads();
    for (int j = e0 + tid; j < e1; j += 256) {
        uint_t p = pairs[j];
        int pos = atomicAdd(&h[p >> 24], 1);
        csr[pos] = (int)(p & 0xffffffu);
    }
    __syncthreads();                              // csr window complete (L2-hot)

    // ---- phase B: gather ----
    int l = tid & 15, g = tid >> 4;
    const char* xb = (const char*)xq + l * 4;
    for (int p = 0; p < 16; ++p) {
        int no = p * 16 + g;                      // node offset in bucket
        int i = d0 + no;
        if (i >= N) continue;
        int r0 = e0 + ((no > 0) ? s[no - 1] : 0);
        int r1 = e0 + s[no];
        float a0 = 0.f, a1 = 0.f, a2 = 0.f, a3 = 0.f;
        for (int bb = r0; bb < r1; bb += 16) {
            int idx = bb + l;
            int src = (idx < r1) ? csr[idx] : N;  // N = zero row
            scr[tid] = src << 6;                  // 64 B fp8 rows
            #pragma unroll
            for (int r = 0; r < 4; ++r) {
                uint4 q = *(const uint4*)&scr[g * 16 + r * 4];
                #pragma unroll
                for (int e = 0; e < 4; ++e) {
                    uint_t off = (e == 0) ? q.x : (e == 1) ? q.y : (e == 2) ? q.z : q.w;
                    uint_t u = *(const uint_t*)(xb + off);
                    f32x2 p0 = __builtin_amdgcn_cvt_pk_f32_fp8((int)u, false);
                    f32x2 p1 = __builtin_amdgcn_cvt_pk_f32_fp8((int)u, true);
                    a0 += p0.x; a1 += p0.y; a2 += p1.x; a3 += p1.y;
                }
            }
        }
        float dn = 1.0f / fmaxf((float)(r1 - r0), 1.0f);
        ushort4 o = { f2bf(a0 * dn), f2bf(a1 * dn), f2bf(a2 * dn), f2bf(a3 * dn) };
        *(ushort4*)(aggh + (size_t)i * 64 + l * 4) = o;
    }
}

// ---------------- P4: MFMA node GEMMs + attention scores ----------------

__global__ __launch_bounds__(256) void k_gemm(const ushort_t* __restrict__ aggh, const ushort_t* __restrict__ xh,
                                              const ushort_t* __restrict__ Wlrt, const ushort_t* __restrict__ Wgt,
                                              const float* __restrict__ b1,
                                              const float* __restrict__ att_src, const float* __restrict__ att_dst,
                                              unsigned char* __restrict__ zq, float* __restrict__ a_s,
                                              float* __restrict__ a_d, int N) {
    __shared__ ushort_t Wls[64 * 136];
    __shared__ ushort_t Wgs[32 * 72];
    __shared__ ushort_t hs[64 * 136];
    int tid = threadIdx.x;
    for (int t = tid; t < 64 * 16; t += 256) {
        int n = t >> 4, cq = t & 15;
        *(uint4*)(&Wls[n * 136 + cq * 8]) = *(const uint4*)(&Wlrt[n * 128 + cq * 8]);
    }
    for (int t = tid; t < 32 * 8; t += 256) {
        int n = t >> 3, cq = t & 7;
        *(uint4*)(&Wgs[n * 72 + cq * 8]) = *(const uint4*)(&Wgt[n * 64 + cq * 8]);
    }
    __syncthreads();

    int w = tid >> 6, lane = tid & 63;
    int c = lane & 15, quad = lane >> 4;
    int m0 = blockIdx.x * 64 + w * 16;
    int row = m0 + c;
    bool rowok = row < N;

    f32x4 acc[4] = {};
    #pragma unroll
    for (int kk = 0; kk < 4; ++kk) {
        const ushort_t* Abase = (kk < 2) ? aggh : xh;
        int koff = (kk & 1) * 32 + quad * 8;
        short8 a = {};
        if (rowok) a = *(const short8*)(Abase + (size_t)row * 64 + koff);
        #pragma unroll
        for (int nb = 0; nb < 4; ++nb) {
            short8 b = *(const short8*)(&Wls[(nb * 16 + c) * 136 + kk * 32 + quad * 8]);
            acc[nb] = __builtin_amdgcn_mfma_f32_16x16x32_bf16(a, b, acc[nb], 0, 0, 0);
        }
    }
    ushort_t* hw = &hs[w * 16 * 136];
    #pragma unroll
    for (int nb = 0; nb < 4; ++nb) {
        float bb = b1[nb * 16 + c];
        #pragma unroll
        for (int r = 0; r < 4; ++r) {
            float h = acc[nb][r] + bb;
            hw[(quad * 4 + r) * 136 + nb * 16 + c] = f2bf(fmaxf(h, 0.f));
        }
    }
    f32x4 acc2[2] = {};
    #pragma unroll
    for (int kk = 0; kk < 2; ++kk) {
        short8 a = *(const short8*)(&hw[c * 136 + kk * 32 + quad * 8]);
        #pragma unroll
        for (int nb = 0; nb < 2; ++nb) {
            short8 b = *(const short8*)(&Wgs[(nb * 16 + c) * 72 + kk * 32 + quad * 8]);
            acc2[nb] = __builtin_amdgcn_mfma_f32_16x16x32_bf16(a, b, acc2[nb], 0, 0, 0);
        }
    }
    float as0 = att_src[c], as1 = att_src[16 + c];
    float ad0 = att_dst[c], ad1 = att_dst[16 + c];
    #pragma unroll
    for (int r = 0; r < 4; ++r) {
        int grow = m0 + quad * 4 + r;
        float z0 = acc2[0][r], z1 = acc2[1][r];
        float ps = z0 * as0 + z1 * as1;
        float pd = z0 * ad0 + z1 * ad1;
        #pragma unroll
        for (int off = 8; off; off >>= 1) {
            ps += __shfl_xor(ps, off, 64);
            pd += __shfl_xor(pd, off, 64);
        }
        if (grow < N) {
            int r8 = __builtin_amdgcn_cvt_pk_fp8_f32(z0, z1, 0, false);
            unsigned char* zrow = zq + (size_t)grow * 32;
            zrow[c] = (unsigned char)(r8 & 0xff);
            zrow[16 + c] = (unsigned char)((r8 >> 8) & 0xff);
            if (c == 0) { a_s[grow] = ps; a_d[grow] = pd; }
        }
    }
}

// ---------------- P5: GAT softmax aggregation + bias + log_softmax ----------------
// 16-lane group per node; LDS-staged (offset, weight); branchless tail via
// zero row (w=0) — no max subtraction (scores bounded, shift-invariant).

__global__ __launch_bounds__(256) void k_gat(const unsigned char* __restrict__ zq, const float* __restrict__ a_s,
                                             const float* __restrict__ a_d, const int* __restrict__ rowptr,
                                             const int* __restrict__ csr, const float* __restrict__ b2,
                                             float* __restrict__ out, int N) {
    __shared__ uint2 scr[256];
    int tid = threadIdx.x;
    int l = tid & 15, g = tid >> 4;
    int i = blockIdx.x * 16 + g;
    if (i >= N) return;
    int r0 = rowptr[i], r1 = rowptr[i + 1];
    float adi = a_d[i], asi = a_s[i];
    const char* zb = (const char*)zq + l * 2;
    float accx = 0.f, accy = 0.f, dsum = 0.f;

    for (int bb = r0; bb < r1; bb += 16) {
        int idx = bb + l;
        bool valid = idx < r1;
        int s_l = valid ? csr[idx] : N;           // N = zero row
        float w_l = 0.f;
        if (valid) {
            float e = a_s[s_l] + adi;
            e = fmaxf(e, 0.2f * e);               // leaky_relu
            w_l = __expf(e);
            dsum += w_l;
        }
        scr[tid] = make_uint2((uint_t)(s_l << 5), __float_as_uint(w_l));
        #pragma unroll
        for (int r = 0; r < 8; ++r) {
            uint4 q = *(const uint4*)&scr[g * 16 + r * 2];
            {
                uint_t u = *(const ushort_t*)(zb + q.x);
                f32x2 p = __builtin_amdgcn_cvt_pk_f32_fp8((int)u, false);
                float w = __uint_as_float(q.y);
                accx += w * p.x; accy += w * p.y;
            }
            {
                uint_t u = *(const ushort_t*)(zb + q.z);
                f32x2 p = __builtin_amdgcn_cvt_pk_f32_fp8((int)u, false);
                float w = __uint_as_float(q.w);
                accx += w * p.x; accy += w * p.y;
            }
        }
    }
    #pragma unroll
    for (int off = 8; off; off >>= 1) dsum += __shfl_xor(dsum, off, 64);
    float es = asi + adi; es = fmaxf(es, 0.2f * es);
    float wse = __expf(es);
    float denom = dsum + wse;
    uint_t us = *(const ushort_t*)((const char*)zq + (size_t)i * 32 + l * 2);
    f32x2 pself = __builtin_amdgcn_cvt_pk_f32_fp8((int)us, false);
    accx += wse * pself.x;
    accy += wse * pself.y;

    float rden = 1.0f / denom;
    float o0 = accx * rden + b2[l * 2];
    float o1 = accy * rden + b2[l * 2 + 1];
    float m2 = fmaxf(o0, o1);
    #pragma unroll
    for (int off = 8; off; off >>= 1) m2 = fmaxf(m2, __shfl_xor(m2, off, 64));
    float ssum = __expf(o0 - m2) + __expf(o1 - m2);
    #pragma unroll
    for (int off = 8; off; off >>= 1) ssum += __shfl_xor(ssum, off, 64);
    float lg = m2 + __logf(ssum);
    float2 r = { o0 - lg, o1 - lg };
    *(float2*)(out + (size_t)i * 32 + l * 2) = r;
}

// ---------------- host launch ----------------

extern "C" void kernel_launch(void* const* d_in, const int* in_sizes, int n_in,
                              void* d_out, int out_size, void* d_ws, size_t ws_size,
                              hipStream_t stream) {
    const float* x       = (const float*)d_in[0];
    const int*   ei      = (const int*)d_in[1];
    const float* Wl      = (const float*)d_in[2];
    const float* Wr      = (const float*)d_in[3];
    const float* b1      = (const float*)d_in[4];
    const float* Wg      = (const float*)d_in[5];
    const float* att_src = (const float*)d_in[6];
    const float* att_dst = (const float*)d_in[7];
    const float* b2      = (const float*)d_in[8];
    float* out = (float*)d_out;

    int N = in_sizes[0] / 64;
    int E = in_sizes[1] / 2;
    int NB = (N + 255) >> 8;

    char* ws = (char*)d_ws;
    size_t off = 0;
    auto alloc = [&](size_t bytes) { size_t r = off; off += (bytes + 255) & ~(size_t)255; return r; };
    int* tot       = (int*)(ws + alloc((size_t)(NB + 1) * 4));
    int* base      = (int*)(ws + alloc((size_t)(NB + 1) * 4));
    int* gofs      = (int*)(ws + alloc((size_t)(NB + 1) * 4));
    int* rowptr    = (int*)(ws + alloc((size_t)(N + 1) * 4));
    uint_t* pairs  = (uint_t*)(ws + alloc((size_t)E * 4));
    int* csr       = (int*)(ws + alloc((size_t)E * 4));
    ushort_t* xh   = (ushort_t*)(ws + alloc((size_t)N * 64 * 2));
    unsigned char* xq = (unsigned char*)(ws + alloc((size_t)(N + 1) * 64));
    ushort_t* aggh = (ushort_t*)(ws + alloc((size_t)N * 64 * 2));
    unsigned char* zq = (unsigned char*)(ws + alloc((size_t)(N + 1) * 32));
    float* a_s     = (float*)(ws + alloc((size_t)N * 4));
    float* a_d     = (float*)(ws + alloc((size_t)N * 4));
    ushort_t* Wlrt = (ushort_t*)(ws + alloc(64 * 128 * 2));
    ushort_t* Wgt  = (ushort_t*)(ws + alloc(32 * 64 * 2));

    (void)hipMemsetAsync(tot, 0, (size_t)NB * 4, stream);

    int nchunk = (E + PART_CHUNK - 1) / PART_CHUNK;
    int n4 = N * 64 / 4;
    int gpre = (n4 + 255) / 256;
    if (gpre < 545) gpre = 545;
    k_pre  <<<gpre, 256, 0, stream>>>(x, xh, xq, ei, tot, Wl, Wr, Wg, Wlrt, Wgt, zq, n4, E, NB, N, nchunk);
    k_scan <<<1, 256, 0, stream>>>(tot, base, gofs, rowptr, NB, E, N);
    k_part <<<nchunk, 256, 0, stream>>>(ei, gofs, pairs, E, NB);
    k_csrg <<<NB, 256, 0, stream>>>(pairs, base, rowptr, csr, xq, aggh, N);
    k_gemm <<<(N + 63) / 64, 256, 0, stream>>>(aggh, xh, Wlrt, Wgt, b1, att_src, att_dst, zq, a_s, a_d, N);
    k_gat  <<<(N + 15) / 16, 256, 0, stream>>>(zq, a_s, a_d, rowptr, csr, b2, out, N);
}

// Round 9
// 206.691 us; speedup vs baseline: 2.4434x; 1.0192x over previous
//
#include <hip/hip_runtime.h>
#include <cstdint>
#include <cstddef>

// GNN: SAGEConv(mean) + GATConv(1 head, self-loops) + log_softmax
// CSR via two-level counting sort. Edge kernels: 16-lane-group per node,
// LDS-staged (offset,weight) broadcast, fp8 e4m3 compressed rows, zero-row
// padding for branchless tails. MFMA node GEMMs. 8 dispatches total.
// R8 lesson: keep latency-bound gather in its own large grid (occupancy!).

typedef unsigned short ushort_t;
typedef unsigned int uint_t;
typedef __attribute__((ext_vector_type(8))) short short8;
typedef __attribute__((ext_vector_type(4))) float f32x4;
typedef __attribute__((ext_vector_type(2))) float f32x2;

__device__ inline ushort_t f2bf(float f) {
    uint_t u = __float_as_uint(f);
    uint_t r = (u + 0x7fffu + ((u >> 16) & 1u)) >> 16;   // RTNE
    return (ushort_t)r;
}

#define PART_CHUNK 8192   // edges per block in cnt / k_part

// ---------------- P0: cvt x -> bf16+fp8, weights -> bf16^T, bucket counts ----------------

__global__ __launch_bounds__(256) void k_pre(const float* __restrict__ x, ushort_t* __restrict__ xh,
                                             unsigned char* __restrict__ xq,
                                             const int* __restrict__ ei, int* __restrict__ tot,
                                             const float* __restrict__ Wl, const float* __restrict__ Wr,
                                             const float* __restrict__ Wg,
                                             ushort_t* __restrict__ Wlrt, ushort_t* __restrict__ Wgt,
                                             unsigned char* __restrict__ zq,
                                             int n4, int E, int NB, int N, int nchunk) {
    __shared__ int h[512];
    int bid = blockIdx.x, tid = threadIdx.x;
    int idx = bid * 256 + tid;
    if (idx < n4) {
        float4 v = ((const float4*)x)[idx];
        ushort4 o = { f2bf(v.x), f2bf(v.y), f2bf(v.z), f2bf(v.w) };
        ((ushort4*)xh)[idx] = o;
        int r = 0;
        r = __builtin_amdgcn_cvt_pk_fp8_f32(v.x, v.y, r, false);
        r = __builtin_amdgcn_cvt_pk_fp8_f32(v.z, v.w, r, true);
        ((uint_t*)xq)[idx] = (uint_t)r;
    }
    if (bid < nchunk) {                         // block-uniform branch: bucket histogram
        for (int b = tid; b < NB; b += 256) h[b] = 0;
        __syncthreads();
        int b0 = bid * PART_CHUNK;
        int b1 = min(b0 + PART_CHUNK, E);
        for (int j = b0 + tid; j < b1; j += 256) atomicAdd(&h[ei[E + j] >> 8], 1);
        __syncthreads();
        for (int b = tid; b < NB; b += 256) if (h[b]) atomicAdd(&tot[b], h[b]);
    } else if (bid == nchunk) {                 // zero rows (branchless tails elsewhere)
        if (tid < 16) ((uint_t*)(xq + (size_t)N * 64))[tid] = 0;
        if (tid < 8)  ((uint_t*)(zq + (size_t)N * 32))[tid] = 0;
    } else if (bid >= 512 && bid < 544) {       // weights -> bf16 transposed [n][k]
        int t = (bid - 512) * 256 + tid;        // 0..8191
        int n = t >> 7, k = t & 127;
        float v = (k < 64) ? Wl[k * 64 + n] : Wr[(k - 64) * 64 + n];
        Wlrt[n * 128 + k] = f2bf(v);
        if (t < 32 * 64) {
            int n2 = t >> 6, k2 = t & 63;
            Wgt[n2 * 64 + k2] = f2bf(Wg[k2 * 32 + n2]);
        }
    }
}

// ---------------- P1: exclusive scan of bucket totals ----------------

__global__ __launch_bounds__(256) void k_scan(const int* __restrict__ tot, int* __restrict__ base,
                                              int* __restrict__ gofs, int* __restrict__ rowptr,
                                              int NB, int E, int N) {
    __shared__ int t[256];
    int tid = threadIdx.x;
    int v0 = (2 * tid < NB) ? tot[2 * tid] : 0;
    int v1 = (2 * tid + 1 < NB) ? tot[2 * tid + 1] : 0;
    t[tid] = v0 + v1;
    __syncthreads();
    for (int off = 1; off < 256; off <<= 1) {
        int u = (tid >= off) ? t[tid - off] : 0;
        __syncthreads();
        t[tid] += u;
        __syncthreads();
    }
    int pairExcl = (tid > 0) ? t[tid - 1] : 0;
    if (2 * tid < NB)     { base[2 * tid] = pairExcl;          gofs[2 * tid] = pairExcl; }
    if (2 * tid + 1 < NB) { base[2 * tid + 1] = pairExcl + v0; gofs[2 * tid + 1] = pairExcl + v0; }
    if (tid == 0) { rowptr[N] = E; base[NB] = E; }
}

// ---------------- P2: partition (src | (dst&255)<<24) bucket-contiguous ----------------

__global__ __launch_bounds__(256) void k_part(const int* __restrict__ ei, int* __restrict__ gofs,
                                              uint_t* __restrict__ pairs, int E, int NB) {
    __shared__ int h[512];
    __shared__ int ofs[512];
    int tid = threadIdx.x;
    for (int b = tid; b < NB; b += 256) h[b] = 0;
    __syncthreads();
    int b0 = blockIdx.x * PART_CHUNK;
    int b1 = min(b0 + PART_CHUNK, E);
    for (int j = b0 + tid; j < b1; j += 256) atomicAdd(&h[ei[E + j] >> 8], 1);
    __syncthreads();
    for (int b = tid; b < NB; b += 256) ofs[b] = h[b] ? atomicAdd(&gofs[b], h[b]) : 0;
    __syncthreads();
    for (int j = b0 + tid; j < b1; j += 256) {
        int d = ei[E + j], s = ei[j];
        int p = atomicAdd(&ofs[d >> 8], 1);
        pairs[p] = (uint_t)s | ((uint_t)(d & 255) << 24);
    }
}

// ---------------- P3: per-bucket CSR build (windowed, L2-hot) ----------------

__global__ __launch_bounds__(256) void k_csr(const uint_t* __restrict__ pairs, const int* __restrict__ base,
                                             int* __restrict__ rowptr, int* __restrict__ csr, int N) {
    __shared__ int h[256];
    __shared__ int s[256];
    int b = blockIdx.x;
    int d0 = b << 8;
    int e0 = base[b], e1 = base[b + 1];
    int tid = threadIdx.x;
    h[tid] = 0;
    __syncthreads();
    for (int j = e0 + tid; j < e1; j += 256) atomicAdd(&h[pairs[j] >> 24], 1);
    __syncthreads();
    int v = h[tid];
    s[tid] = v;
    __syncthreads();
    for (int off = 1; off < 256; off <<= 1) {
        int u = (tid >= off) ? s[tid - off] : 0;
        __syncthreads();
        s[tid] += u;
        __syncthreads();
    }
    int excl = s[tid] - v;
    if (d0 + tid < N) rowptr[d0 + tid] = e0 + excl;
    __syncthreads();
    h[tid] = e0 + excl;
    __syncthreads();
    for (int j = e0 + tid; j < e1; j += 256) {
        uint_t p = pairs[j];
        int pos = atomicAdd(&h[p >> 24], 1);
        csr[pos] = (int)(p & 0xffffffu);
    }
}

// ---------------- P4: SAGE mean aggregation (fp8 rows, LDS-staged offsets) ----------------
// 16-lane group per node (big grid for TLP); lane l owns channels 4l..4l+3.

__global__ __launch_bounds__(256) void k_gather(const int* __restrict__ rowptr, const int* __restrict__ csr,
                                                const unsigned char* __restrict__ xq,
                                                ushort_t* __restrict__ aggh, int N) {
    __shared__ int scr[256];
    int tid = threadIdx.x;
    int l = tid & 15, g = tid >> 4;
    int i = blockIdx.x * 16 + g;
    if (i >= N) return;
    int r0 = rowptr[i], r1 = rowptr[i + 1];
    const char* xb = (const char*)xq + l * 4;
    float a0 = 0.f, a1 = 0.f, a2 = 0.f, a3 = 0.f;
    for (int bb = r0; bb < r1; bb += 16) {
        int idx = bb + l;
        int src = (idx < r1) ? csr[idx] : N;      // N = zero row
        scr[tid] = src << 6;                      // 64 B fp8 rows
        #pragma unroll
        for (int r = 0; r < 4; ++r) {
            uint4 q = *(const uint4*)&scr[g * 16 + r * 4];
            #pragma unroll
            for (int e = 0; e < 4; ++e) {
                uint_t off = (e == 0) ? q.x : (e == 1) ? q.y : (e == 2) ? q.z : q.w;
                uint_t u = *(const uint_t*)(xb + off);
                f32x2 p0 = __builtin_amdgcn_cvt_pk_f32_fp8((int)u, false);
                f32x2 p1 = __builtin_amdgcn_cvt_pk_f32_fp8((int)u, true);
                a0 += p0.x; a1 += p0.y; a2 += p1.x; a3 += p1.y;
            }
        }
    }
    float dn = 1.0f / fmaxf((float)(r1 - r0), 1.0f);
    ushort4 o = { f2bf(a0 * dn), f2bf(a1 * dn), f2bf(a2 * dn), f2bf(a3 * dn) };
    *(ushort4*)(aggh + (size_t)i * 64 + l * 4) = o;
}

// ---------------- P5: MFMA node GEMMs + attention scores ----------------

__global__ __launch_bounds__(256) void k_gemm(const ushort_t* __restrict__ aggh, const ushort_t* __restrict__ xh,
                                              const ushort_t* __restrict__ Wlrt, const ushort_t* __restrict__ Wgt,
                                              const float* __restrict__ b1,
                                              const float* __restrict__ att_src, const float* __restrict__ att_dst,
                                              unsigned char* __restrict__ zq, float* __restrict__ a_s,
                                              float* __restrict__ a_d, int N) {
    __shared__ ushort_t Wls[64 * 136];
    __shared__ ushort_t Wgs[32 * 72];
    __shared__ ushort_t hs[64 * 136];
    int tid = threadIdx.x;
    for (int t = tid; t < 64 * 16; t += 256) {
        int n = t >> 4, cq = t & 15;
        *(uint4*)(&Wls[n * 136 + cq * 8]) = *(const uint4*)(&Wlrt[n * 128 + cq * 8]);
    }
    for (int t = tid; t < 32 * 8; t += 256) {
        int n = t >> 3, cq = t & 7;
        *(uint4*)(&Wgs[n * 72 + cq * 8]) = *(const uint4*)(&Wgt[n * 64 + cq * 8]);
    }
    __syncthreads();

    int w = tid >> 6, lane = tid & 63;
    int c = lane & 15, quad = lane >> 4;
    int m0 = blockIdx.x * 64 + w * 16;
    int row = m0 + c;
    bool rowok = row < N;

    f32x4 acc[4] = {};
    #pragma unroll
    for (int kk = 0; kk < 4; ++kk) {
        const ushort_t* Abase = (kk < 2) ? aggh : xh;
        int koff = (kk & 1) * 32 + quad * 8;
        short8 a = {};
        if (rowok) a = *(const short8*)(Abase + (size_t)row * 64 + koff);
        #pragma unroll
        for (int nb = 0; nb < 4; ++nb) {
            short8 b = *(const short8*)(&Wls[(nb * 16 + c) * 136 + kk * 32 + quad * 8]);
            acc[nb] = __builtin_amdgcn_mfma_f32_16x16x32_bf16(a, b, acc[nb], 0, 0, 0);
        }
    }
    ushort_t* hw = &hs[w * 16 * 136];
    #pragma unroll
    for (int nb = 0; nb < 4; ++nb) {
        float bb = b1[nb * 16 + c];
        #pragma unroll
        for (int r = 0; r < 4; ++r) {
            float h = acc[nb][r] + bb;
            hw[(quad * 4 + r) * 136 + nb * 16 + c] = f2bf(fmaxf(h, 0.f));
        }
    }
    f32x4 acc2[2] = {};
    #pragma unroll
    for (int kk = 0; kk < 2; ++kk) {
        short8 a = *(const short8*)(&hw[c * 136 + kk * 32 + quad * 8]);
        #pragma unroll
        for (int nb = 0; nb < 2; ++nb) {
            short8 b = *(const short8*)(&Wgs[(nb * 16 + c) * 72 + kk * 32 + quad * 8]);
            acc2[nb] = __builtin_amdgcn_mfma_f32_16x16x32_bf16(a, b, acc2[nb], 0, 0, 0);
        }
    }
    float as0 = att_src[c], as1 = att_src[16 + c];
    float ad0 = att_dst[c], ad1 = att_dst[16 + c];
    #pragma unroll
    for (int r = 0; r < 4; ++r) {
        int grow = m0 + quad * 4 + r;
        float z0 = acc2[0][r], z1 = acc2[1][r];
        float ps = z0 * as0 + z1 * as1;
        float pd = z0 * ad0 + z1 * ad1;
        #pragma unroll
        for (int off = 8; off; off >>= 1) {
            ps += __shfl_xor(ps, off, 64);
            pd += __shfl_xor(pd, off, 64);
        }
        if (grow < N) {
            int r8 = __builtin_amdgcn_cvt_pk_fp8_f32(z0, z1, 0, false);
            unsigned char* zrow = zq + (size_t)grow * 32;
            zrow[c] = (unsigned char)(r8 & 0xff);
            zrow[16 + c] = (unsigned char)((r8 >> 8) & 0xff);
            if (c == 0) { a_s[grow] = ps; a_d[grow] = pd; }
        }
    }
}

// ---------------- P6: GAT softmax aggregation + bias + log_softmax ----------------
// 16-lane group per node; LDS-staged (offset, weight); branchless tail via
// zero row (w=0) — no max subtraction (scores bounded, shift-invariant).

__global__ __launch_bounds__(256) void k_gat(const unsigned char* __restrict__ zq, const float* __restrict__ a_s,
                                             const float* __restrict__ a_d, const int* __restrict__ rowptr,
                                             const int* __restrict__ csr, const float* __restrict__ b2,
                                             float* __restrict__ out, int N) {
    __shared__ uint2 scr[256];
    int tid = threadIdx.x;
    int l = tid & 15, g = tid >> 4;
    int i = blockIdx.x * 16 + g;
    if (i >= N) return;
    int r0 = rowptr[i], r1 = rowptr[i + 1];
    float adi = a_d[i], asi = a_s[i];
    const char* zb = (const char*)zq + l * 2;
    float accx = 0.f, accy = 0.f, dsum = 0.f;

    for (int bb = r0; bb < r1; bb += 16) {
        int idx = bb + l;
        bool valid = idx < r1;
        int s_l = valid ? csr[idx] : N;           // N = zero row
        float w_l = 0.f;
        if (valid) {
            float e = a_s[s_l] + adi;
            e = fmaxf(e, 0.2f * e);               // leaky_relu
            w_l = __expf(e);
            dsum += w_l;
        }
        scr[tid] = make_uint2((uint_t)(s_l << 5), __float_as_uint(w_l));
        #pragma unroll
        for (int r = 0; r < 8; ++r) {
            uint4 q = *(const uint4*)&scr[g * 16 + r * 2];
            {
                uint_t u = *(const ushort_t*)(zb + q.x);
                f32x2 p = __builtin_amdgcn_cvt_pk_f32_fp8((int)u, false);
                float w = __uint_as_float(q.y);
                accx += w * p.x; accy += w * p.y;
            }
            {
                uint_t u = *(const ushort_t*)(zb + q.z);
                f32x2 p = __builtin_amdgcn_cvt_pk_f32_fp8((int)u, false);
                float w = __uint_as_float(q.w);
                accx += w * p.x; accy += w * p.y;
            }
        }
    }
    #pragma unroll
    for (int off = 8; off; off >>= 1) dsum += __shfl_xor(dsum, off, 64);
    float es = asi + adi; es = fmaxf(es, 0.2f * es);
    float wse = __expf(es);
    float denom = dsum + wse;
    uint_t us = *(const ushort_t*)((const char*)zq + (size_t)i * 32 + l * 2);
    f32x2 pself = __builtin_amdgcn_cvt_pk_f32_fp8((int)us, false);
    accx += wse * pself.x;
    accy += wse * pself.y;

    float rden = 1.0f / denom;
    float o0 = accx * rden + b2[l * 2];
    float o1 = accy * rden + b2[l * 2 + 1];
    float m2 = fmaxf(o0, o1);
    #pragma unroll
    for (int off = 8; off; off >>= 1) m2 = fmaxf(m2, __shfl_xor(m2, off, 64));
    float ssum = __expf(o0 - m2) + __expf(o1 - m2);
    #pragma unroll
    for (int off = 8; off; off >>= 1) ssum += __shfl_xor(ssum, off, 64);
    float lg = m2 + __logf(ssum);
    float2 r = { o0 - lg, o1 - lg };
    *(float2*)(out + (size_t)i * 32 + l * 2) = r;
}

// ---------------- host launch ----------------

extern "C" void kernel_launch(void* const* d_in, const int* in_sizes, int n_in,
                              void* d_out, int out_size, void* d_ws, size_t ws_size,
                              hipStream_t stream) {
    const float* x       = (const float*)d_in[0];
    const int*   ei      = (const int*)d_in[1];
    const float* Wl      = (const float*)d_in[2];
    const float* Wr      = (const float*)d_in[3];
    const float* b1      = (const float*)d_in[4];
    const float* Wg      = (const float*)d_in[5];
    const float* att_src = (const float*)d_in[6];
    const float* att_dst = (const float*)d_in[7];
    const float* b2      = (const float*)d_in[8];
    float* out = (float*)d_out;

    int N = in_sizes[0] / 64;
    int E = in_sizes[1] / 2;
    int NB = (N + 255) >> 8;

    char* ws = (char*)d_ws;
    size_t off = 0;
    auto alloc = [&](size_t bytes) { size_t r = off; off += (bytes + 255) & ~(size_t)255; return r; };
    int* tot       = (int*)(ws + alloc((size_t)(NB + 1) * 4));
    int* base      = (int*)(ws + alloc((size_t)(NB + 1) * 4));
    int* gofs      = (int*)(ws + alloc((size_t)(NB + 1) * 4));
    int* rowptr    = (int*)(ws + alloc((size_t)(N + 1) * 4));
    uint_t* pairs  = (uint_t*)(ws + alloc((size_t)E * 4));
    int* csr       = (int*)(ws + alloc((size_t)E * 4));
    ushort_t* xh   = (ushort_t*)(ws + alloc((size_t)N * 64 * 2));
    unsigned char* xq = (unsigned char*)(ws + alloc((size_t)(N + 1) * 64));
    ushort_t* aggh = (ushort_t*)(ws + alloc((size_t)N * 64 * 2));
    unsigned char* zq = (unsigned char*)(ws + alloc((size_t)(N + 1) * 32));
    float* a_s     = (float*)(ws + alloc((size_t)N * 4));
    float* a_d     = (float*)(ws + alloc((size_t)N * 4));
    ushort_t* Wlrt = (ushort_t*)(ws + alloc(64 * 128 * 2));
    ushort_t* Wgt  = (ushort_t*)(ws + alloc(32 * 64 * 2));

    (void)hipMemsetAsync(tot, 0, (size_t)NB * 4, stream);

    int nchunk = (E + PART_CHUNK - 1) / PART_CHUNK;
    int n4 = N * 64 / 4;
    int gpre = (n4 + 255) / 256;
    if (gpre < 545) gpre = 545;
    k_pre    <<<gpre, 256, 0, stream>>>(x, xh, xq, ei, tot, Wl, Wr, Wg, Wlrt, Wgt, zq, n4, E, NB, N, nchunk);
    k_scan   <<<1, 256, 0, stream>>>(tot, base, gofs, rowptr, NB, E, N);
    k_part   <<<nchunk, 256, 0, stream>>>(ei, gofs, pairs, E, NB);
    k_csr    <<<NB, 256, 0, stream>>>(pairs, base, rowptr, csr, N);
    k_gather <<<(N + 15) / 16, 256, 0, stream>>>(rowptr, csr, xq, aggh, N);
    k_gemm   <<<(N + 63) / 64, 256, 0, stream>>>(aggh, xh, Wlrt, Wgt, b1, att_src, att_dst, zq, a_s, a_d, N);
    k_gat    <<<(N + 15) / 16, 256, 0, stream>>>(zq, a_s, a_d, rowptr, csr, b2, out, N);
}